// Round 2
// baseline (438.061 us; speedup 1.0000x reference)
//
#include <hip/hip_runtime.h>
#include <hip/hip_bf16.h>

#define WW 128
#define GG 64
#define GN_EPS 1e-5f
#define SCAN_B 1024

typedef __attribute__((ext_vector_type(8))) short short8;
typedef __attribute__((ext_vector_type(4))) float floatx4;

__device__ inline float bf2f(__hip_bfloat16 h) { return __bfloat162float(h); }

// ---------------- GraphNorm stats: per-graph sum, sumsq, count ----------------
// 4-row batched loads (8 independent loads in flight) before the serial
// boundary logic; graph boundaries are rare (63 total across the dataset).
__global__ __launch_bounds__(128) void stats_kernel(
    const float* __restrict__ x, const int* __restrict__ batch, int N,
    float* __restrict__ gsum, float* __restrict__ gsumsq, float* __restrict__ gcnt)
{
    int w = threadIdx.x;
    int row0 = blockIdx.x * 64;
    int row1 = min(row0 + 64, N);
    float s = 0.f, ss = 0.f;
    int cur = batch[row0];
    int cnt = 0;
    auto flush = [&]() {
        atomicAdd(&gsum[cur * WW + w], s);
        atomicAdd(&gsumsq[cur * WW + w], ss);
        if (w == 0) atomicAdd(&gcnt[cur], (float)cnt);
        s = 0.f; ss = 0.f; cnt = 0;
    };
    int i = row0;
    for (; i + 4 <= row1; i += 4) {
        int g0 = batch[i + 0], g1 = batch[i + 1], g2 = batch[i + 2], g3 = batch[i + 3];
        float v0 = x[(size_t)(i + 0) * WW + w];
        float v1 = x[(size_t)(i + 1) * WW + w];
        float v2 = x[(size_t)(i + 2) * WW + w];
        float v3 = x[(size_t)(i + 3) * WW + w];
        if (g0 != cur) { flush(); cur = g0; }
        s += v0; ss += v0 * v0; ++cnt;
        if (g1 != cur) { flush(); cur = g1; }
        s += v1; ss += v1 * v1; ++cnt;
        if (g2 != cur) { flush(); cur = g2; }
        s += v2; ss += v2 * v2; ++cnt;
        if (g3 != cur) { flush(); cur = g3; }
        s += v3; ss += v3 * v3; ++cnt;
    }
    for (; i < row1; ++i) {
        int g = batch[i];
        float v = x[(size_t)i * WW + w];
        if (g != cur) { flush(); cur = g; }
        s += v; ss += v * v; ++cnt;
    }
    flush();
}

// ---------------- fold stats into per-(g,w) affine scale/shift ----------------
__global__ __launch_bounds__(256) void finalize_kernel(
    const float* __restrict__ gsum, const float* __restrict__ gsumsq,
    const float* __restrict__ gcnt,
    const float* __restrict__ wgt, const float* __restrict__ bias,
    const float* __restrict__ ms,
    float* __restrict__ scalev, float* __restrict__ shiftv)
{
    int idx = blockIdx.x * blockDim.x + threadIdx.x;
    if (idx >= GG * WW) return;
    int g = idx >> 7, w = idx & (WW - 1);
    float cnt = gcnt[g];
    float inv = cnt > 0.f ? 1.f / cnt : 0.f;
    float mean = gsum[idx] * inv;
    float msw = ms[w];
    float var = gsumsq[idx] * inv - mean * mean * msw * (2.f - msw);
    var = fmaxf(var, 0.f);
    float sc = wgt[w] * rsqrtf(var + GN_EPS);
    scalev[idx] = sc;
    shiftv[idx] = bias[w] - sc * msw * mean;
}

// ---------------- normalize: xn = scale*x + shift (bf16 out), float4 lanes ----
__global__ __launch_bounds__(256) void normalize_kernel(
    const float* __restrict__ x, const int* __restrict__ batch,
    const float* __restrict__ scalev, const float* __restrict__ shiftv,
    __hip_bfloat16* __restrict__ xn, int N)
{
    size_t tid = (size_t)blockIdx.x * blockDim.x + threadIdx.x;   // one per 4 elems
    if (tid >= (size_t)N * (WW / 4)) return;
    int row = (int)(tid >> 5);
    int c4 = (int)(tid & 31) * 4;
    int g = batch[row];
    float4 v = *(const float4*)(x + (size_t)row * WW + c4);
    float4 sc = *(const float4*)(scalev + (size_t)g * WW + c4);
    float4 sh = *(const float4*)(shiftv + (size_t)g * WW + c4);
    __hip_bfloat162 o0, o1;
    o0.x = __float2bfloat16(sc.x * v.x + sh.x);
    o0.y = __float2bfloat16(sc.y * v.y + sh.y);
    o1.x = __float2bfloat16(sc.z * v.z + sh.z);
    o1.y = __float2bfloat16(sc.w * v.w + sh.w);
    union { __hip_bfloat162 h[2]; uint2 u; } pk;
    pk.h[0] = o0; pk.h[1] = o1;
    *(uint2*)(xn + (size_t)row * WW + c4) = pk.u;
}

// ---------------- convert fp32 weight matrices -> bf16 ----------------
__global__ __launch_bounds__(256) void cvt_w_kernel(
    const float* __restrict__ w0, const float* __restrict__ w1,
    const float* __restrict__ w2, const float* __restrict__ w3,
    __hip_bfloat16* __restrict__ dst)
{
    int idx = blockIdx.x * blockDim.x + threadIdx.x;   // 0 .. 4*16384-1
    int m = idx >> 14;
    int o = idx & 16383;
    const float* src = (m == 0) ? w0 : (m == 1) ? w1 : (m == 2) ? w2 : w3;
    dst[idx] = __float2bfloat16(src[o]);
}

// ---------------- CSR build: histogram over dst ----------------
__global__ __launch_bounds__(256) void hist_kernel(
    const int* __restrict__ ei, int E, int* __restrict__ deg)
{
    int e = blockIdx.x * 256 + threadIdx.x;
    if (e < E) atomicAdd(&deg[ei[(size_t)E + e]], 1);
}

// ---------------- hierarchical exclusive scan (3 kernels) ----------------
__global__ __launch_bounds__(SCAN_B) void scan_blocks(
    const int* __restrict__ deg, int N, int* __restrict__ off, int* __restrict__ bsum)
{
    __shared__ int s[SCAN_B];
    int t = threadIdx.x;
    int i = blockIdx.x * SCAN_B + t;
    int v = (i < N) ? deg[i] : 0;
    s[t] = v; __syncthreads();
    for (int d = 1; d < SCAN_B; d <<= 1) {
        int tmp = (t >= d) ? s[t - d] : 0;
        __syncthreads();
        s[t] += tmp;
        __syncthreads();
    }
    if (i < N) off[i] = s[t] - v;                 // block-local exclusive
    if (t == SCAN_B - 1) bsum[blockIdx.x] = s[t]; // block total
}

__global__ __launch_bounds__(256) void scan_partials(int* __restrict__ bsum, int P)
{
    __shared__ int s[256];
    int t = threadIdx.x;
    int v = (t < P) ? bsum[t] : 0;
    s[t] = v; __syncthreads();
    for (int d = 1; d < 256; d <<= 1) {
        int tmp = (t >= d) ? s[t - d] : 0;
        __syncthreads();
        s[t] += tmp;
        __syncthreads();
    }
    if (t < P) bsum[t] = s[t] - v;                // exclusive, in place
}

__global__ __launch_bounds__(SCAN_B) void add_offsets(
    int* __restrict__ off, const int* __restrict__ bsum, int N)
{
    int i = blockIdx.x * SCAN_B + threadIdx.x;
    if (i < N) off[i] += bsum[blockIdx.x];
}

// ---------------- placement: ebuf[slot] = {src, weight} bucketed by dst ------
__global__ __launch_bounds__(256) void place_kernel(
    const int* __restrict__ ei, const float* __restrict__ ew,
    const int* __restrict__ off, int* __restrict__ cursor,
    int2* __restrict__ ebuf, int E)
{
    int e = blockIdx.x * 256 + threadIdx.x;
    if (e >= E) return;
    int dst = ei[(size_t)E + e];
    int slot = off[dst] + atomicAdd(&cursor[dst], 1);
    ebuf[slot] = make_int2(ei[e], __float_as_int(ew[e]));
}

// ---------------- gather v5: masked 4-wide main loop, no serial tail ----------
// One wave per node; lane owns 2 channels (bf16x2). Every iteration issues 4
// independent ebuf reads + 4 independent row loads; overhang lanes clamp to
// the last edge and multiply by weight 0 (cache-hit, no extra latency chain).
__global__ __launch_bounds__(256) void gather_kernel(
    const __hip_bfloat16* __restrict__ feat, const int2* __restrict__ ebuf,
    const int* __restrict__ off, const int* __restrict__ deg,
    __hip_bfloat16* __restrict__ aggbf, int N)
{
    int wave = threadIdx.x >> 6;
    int lane = threadIdx.x & 63;
    int node = blockIdx.x * 4 + wave;
    if (node >= N) return;
    int start = off[node];
    int d = deg[node];
    const __hip_bfloat162* f2 = (const __hip_bfloat162*)feat;

    float ax0 = 0.f, ay0 = 0.f, ax1 = 0.f, ay1 = 0.f;
    float ax2 = 0.f, ay2 = 0.f, ax3 = 0.f, ay3 = 0.f;
    int last = start + d - 1;                     // d==0 -> loop skipped
    for (int k = start; k <= last; k += 4) {
        int i1 = min(k + 1, last);
        int i2 = min(k + 2, last);
        int i3 = min(k + 3, last);
        int2 p0 = ebuf[k];
        int2 p1 = ebuf[i1];
        int2 p2 = ebuf[i2];
        int2 p3 = ebuf[i3];
        __hip_bfloat162 v0 = f2[(size_t)p0.x * 64 + lane];
        __hip_bfloat162 v1 = f2[(size_t)p1.x * 64 + lane];
        __hip_bfloat162 v2 = f2[(size_t)p2.x * 64 + lane];
        __hip_bfloat162 v3 = f2[(size_t)p3.x * 64 + lane];
        float w0 = __int_as_float(p0.y);
        float w1 = (k + 1 <= last) ? __int_as_float(p1.y) : 0.f;
        float w2 = (k + 2 <= last) ? __int_as_float(p2.y) : 0.f;
        float w3 = (k + 3 <= last) ? __int_as_float(p3.y) : 0.f;
        ax0 += w0 * bf2f(v0.x); ay0 += w0 * bf2f(v0.y);
        ax1 += w1 * bf2f(v1.x); ay1 += w1 * bf2f(v1.y);
        ax2 += w2 * bf2f(v2.x); ay2 += w2 * bf2f(v2.y);
        ax3 += w3 * bf2f(v3.x); ay3 += w3 * bf2f(v3.y);
    }
    float ax = (ax0 + ax1) + (ax2 + ax3);
    float ay = (ay0 + ay1) + (ay2 + ay3);

    __hip_bfloat162 o;
    o.x = __float2bfloat16(ax);
    o.y = __float2bfloat16(ay);
    ((__hip_bfloat162*)(aggbf + (size_t)node * WW))[lane] = o;
}

// ---------------- fused GEMM v6: 128-row tiles, 2x per-wave MLP --------------
// y = act([A1|A2] @ [Wrel;Wroot]^T + b) (+resid). K=256. Wave owns 32 cols x
// 128 rows (acc[8][2]). Each kc stage now issues 10 independent 1KB load
// instructions (8 A rows + 2 W frags) before any MFMA consumes them — double
// the in-flight bytes per vmcnt wait vs v5 (R1 showed occupancy is NOT the
// limiter; per-wave MLP is). Halves block count (782) -> halves per-block W
// re-fetch too. launch_bounds(256,3) (~170-reg cap) guarantees no hot-loop
// spill at ~130 unified regs; occupancy cap 12 waves/CU ~= measured anyway.
// C/D layout: col=lane&15, row=(lane>>4)*4+reg (m89-verified).
template <bool OUT_BF16>
__global__ __launch_bounds__(256, 3) void gemm_kernel(
    const __hip_bfloat16* __restrict__ A1, const __hip_bfloat16* __restrict__ A2,
    const __hip_bfloat16* __restrict__ Wrel, const __hip_bfloat16* __restrict__ Wroot,
    const float* __restrict__ bias, const float* __restrict__ resid,
    void* __restrict__ outv, int N, int leaky)
{
    int wave = threadIdx.x >> 6;
    int lane = threadIdx.x & 63;
    int q = lane >> 4;
    int r16 = lane & 15;
    int rb = blockIdx.x * 128;

    floatx4 acc[8][2];
#pragma unroll
    for (int r = 0; r < 8; ++r)
#pragma unroll
        for (int tt = 0; tt < 2; ++tt) acc[r][tt] = (floatx4){0.f, 0.f, 0.f, 0.f};

#pragma unroll
    for (int kc = 0; kc < 8; ++kc) {
        const __hip_bfloat16* Asel = (kc < 4) ? A1 : A2;
        const __hip_bfloat16* Wsel = (kc < 4) ? Wrel : Wroot;
        int koff = (kc & 3) * 32 + q * 8;
        short8 wf0 = *(const short8*)(Wsel + ((size_t)((wave * 2 + 0) * 16 + r16) * WW + koff));
        short8 wf1 = *(const short8*)(Wsel + ((size_t)((wave * 2 + 1) * 16 + r16) * WW + koff));
        short8 af[8];
#pragma unroll
        for (int r = 0; r < 8; ++r) {
            int ar = rb + r * 16 + r16;
            if (ar >= N) ar = N - 1;       // clamp loads; stores masked
            af[r] = *(const short8*)(Asel + ((size_t)ar * WW + koff));
        }
#pragma unroll
        for (int r = 0; r < 8; ++r) {
            acc[r][0] = __builtin_amdgcn_mfma_f32_16x16x32_bf16(af[r], wf0, acc[r][0], 0, 0, 0);
            acc[r][1] = __builtin_amdgcn_mfma_f32_16x16x32_bf16(af[r], wf1, acc[r][1], 0, 0, 0);
        }
    }

    float bcol[2];
#pragma unroll
    for (int tt = 0; tt < 2; ++tt) bcol[tt] = bias[(wave * 2 + tt) * 16 + r16];

#pragma unroll
    for (int tt = 0; tt < 2; ++tt) {
        int col = (wave * 2 + tt) * 16 + r16;
#pragma unroll
        for (int r = 0; r < 8; ++r)
#pragma unroll
            for (int rr = 0; rr < 4; ++rr) {
                int row = rb + r * 16 + q * 4 + rr;
                if (row < N) {
                    float v = acc[r][tt][rr] + bcol[tt];
                    if (leaky) v = v >= 0.f ? v : 0.1f * v;
                    if (resid) v += resid[(size_t)row * WW + col];
                    if (OUT_BF16)
                        ((__hip_bfloat16*)outv)[(size_t)row * WW + col] = __float2bfloat16(v);
                    else
                        ((float*)outv)[(size_t)row * WW + col] = v;
                }
            }
    }
}

extern "C" void kernel_launch(void* const* d_in, const int* in_sizes, int n_in,
                              void* d_out, int out_size, void* d_ws, size_t ws_size,
                              hipStream_t stream) {
    const float* x      = (const float*)d_in[0];
    const int*   ei     = (const int*)d_in[1];
    const float* ew     = (const float*)d_in[2];
    const int*   batch  = (const int*)d_in[3];
    const float* gnw    = (const float*)d_in[4];
    const float* gnb    = (const float*)d_in[5];
    const float* gnm    = (const float*)d_in[6];
    const float* Wrel1  = (const float*)d_in[7];
    const float* brel1  = (const float*)d_in[8];
    const float* Wroot1 = (const float*)d_in[9];
    const float* Wrel2  = (const float*)d_in[10];
    const float* brel2  = (const float*)d_in[11];
    const float* Wroot2 = (const float*)d_in[12];

    int N = in_sizes[0] / WW;
    int E = in_sizes[1] / 2;
    int P = (N + SCAN_B - 1) / SCAN_B;   // scan partial count (98 for N=100k)
    int ntiles = (N + 127) / 128;        // 128-row tiles for gemm v6

    // workspace layout (8-byte aligned):
    // aggbf | xn | y1 (bf16 N*W each) | Wb (bf16 4*W*W) | ebuf (int2 E)
    // | deg | cursor | gsum | gsumsq | gcnt | scalev | shiftv | off | bsum
    __hip_bfloat16* aggbf = (__hip_bfloat16*)d_ws;
    __hip_bfloat16* xn = aggbf + (size_t)N * WW;
    __hip_bfloat16* y1 = xn + (size_t)N * WW;
    __hip_bfloat16* Wb = y1 + (size_t)N * WW;       // [Wrel1|Wroot1|Wrel2|Wroot2]
    int2* ebuf   = (int2*)(Wb + 4 * WW * WW);
    int*  deg    = (int*)(ebuf + E);
    int*  cursor = deg + N;
    float* gsum   = (float*)(cursor + N);
    float* gsumsq = gsum + GG * WW;
    float* gcnt   = gsumsq + GG * WW;               // GG floats
    float* scalev = gcnt + GG;
    float* shiftv = scalev + GG * WW;
    int*  off    = (int*)(shiftv + GG * WW);
    int*  bsum   = off + N;

    // one memset covers deg, cursor, gsum, gsumsq, gcnt (contiguous)
    hipMemsetAsync(deg, 0, ((size_t)2 * N + 2 * GG * WW + GG) * sizeof(int), stream);

    // ---- CSR build (once; reused by both layers) ----
    hist_kernel<<<(E + 255) / 256, 256, 0, stream>>>(ei, E, deg);
    scan_blocks<<<P, SCAN_B, 0, stream>>>(deg, N, off, bsum);
    scan_partials<<<1, 256, 0, stream>>>(bsum, P);
    add_offsets<<<P, SCAN_B, 0, stream>>>(off, bsum, N);
    place_kernel<<<(E + 255) / 256, 256, 0, stream>>>(ei, ew, off, cursor, ebuf, E);

    // ---- GraphNorm ----
    cvt_w_kernel<<<(4 * WW * WW) / 256, 256, 0, stream>>>(Wrel1, Wroot1, Wrel2, Wroot2, Wb);
    stats_kernel<<<(N + 63) / 64, 128, 0, stream>>>(x, batch, N, gsum, gsumsq, gcnt);
    finalize_kernel<<<(GG * WW + 255) / 256, 256, 0, stream>>>(
        gsum, gsumsq, gcnt, gnw, gnb, gnm, scalev, shiftv);
    normalize_kernel<<<(int)(((size_t)N * (WW / 4) + 255) / 256), 256, 0, stream>>>(
        x, batch, scalev, shiftv, xn, N);

    // ---- layer 1: gather + GEMM(+bias+leaky) ----
    gather_kernel<<<(N + 3) / 4, 256, 0, stream>>>(xn, ebuf, off, deg, aggbf, N);
    gemm_kernel<true><<<ntiles, 256, 0, stream>>>(
        aggbf, xn, Wb, Wb + WW * WW, brel1, nullptr, y1, N, 1);

    // ---- layer 2: gather + GEMM(+bias+residual) ----
    gather_kernel<<<(N + 3) / 4, 256, 0, stream>>>(y1, ebuf, off, deg, aggbf, N);
    gemm_kernel<false><<<ntiles, 256, 0, stream>>>(
        aggbf, y1, Wb + 2 * WW * WW, Wb + 3 * WW * WW, brel2, x, d_out, N, 0);
}

// Round 3
// 372.208 us; speedup vs baseline: 1.1769x; 1.1769x over previous
//
#include <hip/hip_runtime.h>
#include <hip/hip_bf16.h>

#define WW 128
#define GG 64
#define GN_EPS 1e-5f
#define SCAN_B 1024

typedef __attribute__((ext_vector_type(8))) short short8;
typedef __attribute__((ext_vector_type(4))) float floatx4;

__device__ inline float bf2f(__hip_bfloat16 h) { return __bfloat162float(h); }

// ---------------- GraphNorm stats: per-graph sum, sumsq, count ----------------
__global__ __launch_bounds__(128) void stats_kernel(
    const float* __restrict__ x, const int* __restrict__ batch, int N,
    float* __restrict__ gsum, float* __restrict__ gsumsq, float* __restrict__ gcnt)
{
    int w = threadIdx.x;
    int row0 = blockIdx.x * 64;
    int row1 = min(row0 + 64, N);
    float s = 0.f, ss = 0.f;
    int cur = batch[row0];
    int cnt = 0;
    auto flush = [&]() {
        atomicAdd(&gsum[cur * WW + w], s);
        atomicAdd(&gsumsq[cur * WW + w], ss);
        if (w == 0) atomicAdd(&gcnt[cur], (float)cnt);
        s = 0.f; ss = 0.f; cnt = 0;
    };
    int i = row0;
    for (; i + 4 <= row1; i += 4) {
        int g0 = batch[i + 0], g1 = batch[i + 1], g2 = batch[i + 2], g3 = batch[i + 3];
        float v0 = x[(size_t)(i + 0) * WW + w];
        float v1 = x[(size_t)(i + 1) * WW + w];
        float v2 = x[(size_t)(i + 2) * WW + w];
        float v3 = x[(size_t)(i + 3) * WW + w];
        if (g0 != cur) { flush(); cur = g0; }
        s += v0; ss += v0 * v0; ++cnt;
        if (g1 != cur) { flush(); cur = g1; }
        s += v1; ss += v1 * v1; ++cnt;
        if (g2 != cur) { flush(); cur = g2; }
        s += v2; ss += v2 * v2; ++cnt;
        if (g3 != cur) { flush(); cur = g3; }
        s += v3; ss += v3 * v3; ++cnt;
    }
    for (; i < row1; ++i) {
        int g = batch[i];
        float v = x[(size_t)i * WW + w];
        if (g != cur) { flush(); cur = g; }
        s += v; ss += v * v; ++cnt;
    }
    flush();
}

// ---------------- fold stats into per-(g,w) affine scale/shift ----------------
__global__ __launch_bounds__(256) void finalize_kernel(
    const float* __restrict__ gsum, const float* __restrict__ gsumsq,
    const float* __restrict__ gcnt,
    const float* __restrict__ wgt, const float* __restrict__ bias,
    const float* __restrict__ ms,
    float* __restrict__ scalev, float* __restrict__ shiftv)
{
    int idx = blockIdx.x * blockDim.x + threadIdx.x;
    if (idx >= GG * WW) return;
    int g = idx >> 7, w = idx & (WW - 1);
    float cnt = gcnt[g];
    float inv = cnt > 0.f ? 1.f / cnt : 0.f;
    float mean = gsum[idx] * inv;
    float msw = ms[w];
    float var = gsumsq[idx] * inv - mean * mean * msw * (2.f - msw);
    var = fmaxf(var, 0.f);
    float sc = wgt[w] * rsqrtf(var + GN_EPS);
    scalev[idx] = sc;
    shiftv[idx] = bias[w] - sc * msw * mean;
}

// ---------------- normalize: xn = scale*x + shift (bf16 out), float4 lanes ----
__global__ __launch_bounds__(256) void normalize_kernel(
    const float* __restrict__ x, const int* __restrict__ batch,
    const float* __restrict__ scalev, const float* __restrict__ shiftv,
    __hip_bfloat16* __restrict__ xn, int N)
{
    size_t tid = (size_t)blockIdx.x * blockDim.x + threadIdx.x;   // one per 4 elems
    if (tid >= (size_t)N * (WW / 4)) return;
    int row = (int)(tid >> 5);
    int c4 = (int)(tid & 31) * 4;
    int g = batch[row];
    float4 v = *(const float4*)(x + (size_t)row * WW + c4);
    float4 sc = *(const float4*)(scalev + (size_t)g * WW + c4);
    float4 sh = *(const float4*)(shiftv + (size_t)g * WW + c4);
    __hip_bfloat162 o0, o1;
    o0.x = __float2bfloat16(sc.x * v.x + sh.x);
    o0.y = __float2bfloat16(sc.y * v.y + sh.y);
    o1.x = __float2bfloat16(sc.z * v.z + sh.z);
    o1.y = __float2bfloat16(sc.w * v.w + sh.w);
    union { __hip_bfloat162 h[2]; uint2 u; } pk;
    pk.h[0] = o0; pk.h[1] = o1;
    *(uint2*)(xn + (size_t)row * WW + c4) = pk.u;
}

// ---------------- convert fp32 weight matrices -> bf16 ----------------
__global__ __launch_bounds__(256) void cvt_w_kernel(
    const float* __restrict__ w0, const float* __restrict__ w1,
    const float* __restrict__ w2, const float* __restrict__ w3,
    __hip_bfloat16* __restrict__ dst)
{
    int idx = blockIdx.x * blockDim.x + threadIdx.x;   // 0 .. 4*16384-1
    int m = idx >> 14;
    int o = idx & 16383;
    const float* src = (m == 0) ? w0 : (m == 1) ? w1 : (m == 2) ? w2 : w3;
    dst[idx] = __float2bfloat16(src[o]);
}

// ---------------- CSR build: histogram over dst ----------------
__global__ __launch_bounds__(256) void hist_kernel(
    const int* __restrict__ ei, int E, int* __restrict__ deg)
{
    int e = blockIdx.x * 256 + threadIdx.x;
    if (e < E) atomicAdd(&deg[ei[(size_t)E + e]], 1);
}

// ---------------- hierarchical exclusive scan (3 kernels) ----------------
__global__ __launch_bounds__(SCAN_B) void scan_blocks(
    const int* __restrict__ deg, int N, int* __restrict__ off, int* __restrict__ bsum)
{
    __shared__ int s[SCAN_B];
    int t = threadIdx.x;
    int i = blockIdx.x * SCAN_B + t;
    int v = (i < N) ? deg[i] : 0;
    s[t] = v; __syncthreads();
    for (int d = 1; d < SCAN_B; d <<= 1) {
        int tmp = (t >= d) ? s[t - d] : 0;
        __syncthreads();
        s[t] += tmp;
        __syncthreads();
    }
    if (i < N) off[i] = s[t] - v;                 // block-local exclusive
    if (t == SCAN_B - 1) bsum[blockIdx.x] = s[t]; // block total
}

__global__ __launch_bounds__(256) void scan_partials(int* __restrict__ bsum, int P)
{
    __shared__ int s[256];
    int t = threadIdx.x;
    int v = (t < P) ? bsum[t] : 0;
    s[t] = v; __syncthreads();
    for (int d = 1; d < 256; d <<= 1) {
        int tmp = (t >= d) ? s[t - d] : 0;
        __syncthreads();
        s[t] += tmp;
        __syncthreads();
    }
    if (t < P) bsum[t] = s[t] - v;                // exclusive, in place
}

__global__ __launch_bounds__(SCAN_B) void add_offsets(
    int* __restrict__ off, const int* __restrict__ bsum, int N)
{
    int i = blockIdx.x * SCAN_B + threadIdx.x;
    if (i < N) off[i] += bsum[blockIdx.x];
}

// ---------------- placement: ebuf[slot] = {src, weight} bucketed by dst ------
__global__ __launch_bounds__(256) void place_kernel(
    const int* __restrict__ ei, const float* __restrict__ ew,
    const int* __restrict__ off, int* __restrict__ cursor,
    int2* __restrict__ ebuf, int E)
{
    int e = blockIdx.x * 256 + threadIdx.x;
    if (e >= E) return;
    int dst = ei[(size_t)E + e];
    int slot = off[dst] + atomicAdd(&cursor[dst], 1);
    ebuf[slot] = make_int2(ei[e], __float_as_int(ew[e]));
}

// ---------------- gather v5: masked 4-wide main loop, no serial tail ----------
__global__ __launch_bounds__(256) void gather_kernel(
    const __hip_bfloat16* __restrict__ feat, const int2* __restrict__ ebuf,
    const int* __restrict__ off, const int* __restrict__ deg,
    __hip_bfloat16* __restrict__ aggbf, int N)
{
    int wave = threadIdx.x >> 6;
    int lane = threadIdx.x & 63;
    int node = blockIdx.x * 4 + wave;
    if (node >= N) return;
    int start = off[node];
    int d = deg[node];
    const __hip_bfloat162* f2 = (const __hip_bfloat162*)feat;

    float ax0 = 0.f, ay0 = 0.f, ax1 = 0.f, ay1 = 0.f;
    float ax2 = 0.f, ay2 = 0.f, ax3 = 0.f, ay3 = 0.f;
    int last = start + d - 1;                     // d==0 -> loop skipped
    for (int k = start; k <= last; k += 4) {
        int i1 = min(k + 1, last);
        int i2 = min(k + 2, last);
        int i3 = min(k + 3, last);
        int2 p0 = ebuf[k];
        int2 p1 = ebuf[i1];
        int2 p2 = ebuf[i2];
        int2 p3 = ebuf[i3];
        __hip_bfloat162 v0 = f2[(size_t)p0.x * 64 + lane];
        __hip_bfloat162 v1 = f2[(size_t)p1.x * 64 + lane];
        __hip_bfloat162 v2 = f2[(size_t)p2.x * 64 + lane];
        __hip_bfloat162 v3 = f2[(size_t)p3.x * 64 + lane];
        float w0 = __int_as_float(p0.y);
        float w1 = (k + 1 <= last) ? __int_as_float(p1.y) : 0.f;
        float w2 = (k + 2 <= last) ? __int_as_float(p2.y) : 0.f;
        float w3 = (k + 3 <= last) ? __int_as_float(p3.y) : 0.f;
        ax0 += w0 * bf2f(v0.x); ay0 += w0 * bf2f(v0.y);
        ax1 += w1 * bf2f(v1.x); ay1 += w1 * bf2f(v1.y);
        ax2 += w2 * bf2f(v2.x); ay2 += w2 * bf2f(v2.y);
        ax3 += w3 * bf2f(v3.x); ay3 += w3 * bf2f(v3.y);
    }
    float ax = (ax0 + ax1) + (ax2 + ax3);
    float ay = (ay0 + ay1) + (ay2 + ay3);

    __hip_bfloat162 o;
    o.x = __float2bfloat16(ax);
    o.y = __float2bfloat16(ay);
    ((__hip_bfloat162*)(aggbf + (size_t)node * WW))[lane] = o;
}

// ---------------- fused GEMM v7: LDS tile via global_load_lds ---------------
// y = act([A1|A2] @ [Wrel;Wroot]^T + b) (+resid). K=256, 64-row tiles.
// R0-R2 showed reg-staged scattered loads are latency-serialized (dur*occ ~=
// const; BW pinned at 1.7 TB/s). v7 stages the whole A-tile (A1+A2, 32 KB)
// with 32x coalesced 1KB global_load_lds (fire-and-forget: in-flight bytes
// decoupled from VGPRs), one __syncthreads (emits the vmcnt(0) drain), then
// all 8 K-steps run from LDS with ZERO loop VMEM. W cached in regs (64 VGPR),
// loads overlap staging.
// LDS swizzle (rule #21, both-sides involution): 16B slot s of row r stores
// global chunk s^(r&15); reader XORs the same. Staging stays 1KB-contiguous
// (per-row slot permutation only); frag ds_read_b128 banks are uniform
// (8 slots/bank = bandwidth floor) since (s16^r16)&7 spans 0..7 evenly.
// C/D layout: col=lane&15, row=(lane>>4)*4+reg (m89-verified).
template <bool OUT_BF16>
__global__ __launch_bounds__(256, 3) void gemm_kernel(
    const __hip_bfloat16* __restrict__ A1, const __hip_bfloat16* __restrict__ A2,
    const __hip_bfloat16* __restrict__ Wrel, const __hip_bfloat16* __restrict__ Wroot,
    const float* __restrict__ bias, const float* __restrict__ resid,
    void* __restrict__ outv, int N, int leaky)
{
    __shared__ __hip_bfloat16 smem[2 * 64 * 128];   // 32 KB: [m][row][col-swz]
    int wave = threadIdx.x >> 6;
    int lane = threadIdx.x & 63;
    int q = lane >> 4;
    int r16 = lane & 15;
    int rb = blockIdx.x * 64;

    // ---- stage: instr t = wave*8+s covers matrix m=t>>4, rows (t&15)*4..+3.
    // lane i: row=(t&15)*4+(i>>4), fetches global chunk c=(i&15)^(row&15);
    // HW writes LDS base+i*16 (linear) -> slot d=i&15 holds chunk d^(row&15).
#pragma unroll
    for (int s = 0; s < 8; ++s) {
        int t = wave * 8 + s;
        const __hip_bfloat16* Asel = (t < 16) ? A1 : A2;
        int t4 = t & 15;
        int rloc = t4 * 4 + (lane >> 4);
        int c = (lane & 15) ^ (rloc & 15);
        int grow = rb + rloc; if (grow >= N) grow = N - 1;   // clamp; stores masked
        const __hip_bfloat16* g = Asel + (size_t)grow * WW + c * 8;
        __hip_bfloat16* l = smem + (t >> 4) * 8192 + t4 * 512;   // wave-uniform
        __builtin_amdgcn_global_load_lds(
            (const __attribute__((address_space(1))) void*)g,
            (__attribute__((address_space(3))) void*)l, 16, 0, 0);
    }

    // ---- W fragments to registers (overlap the staging loads) ----
    short8 wf[8][2];
#pragma unroll
    for (int kc = 0; kc < 8; ++kc) {
        const __hip_bfloat16* Wsel = (kc < 4) ? Wrel : Wroot;
        int koff = (kc & 3) * 32 + q * 8;
#pragma unroll
        for (int tt = 0; tt < 2; ++tt) {
            int col = (wave * 2 + tt) * 16 + r16;
            wf[kc][tt] = *(const short8*)(Wsel + ((size_t)col * WW + koff));
        }
    }
    float bcol[2];
#pragma unroll
    for (int tt = 0; tt < 2; ++tt) bcol[tt] = bias[(wave * 2 + tt) * 16 + r16];

    __syncthreads();   // compiler emits s_waitcnt vmcnt(0): LDS tile ready

    floatx4 acc[4][2];
#pragma unroll
    for (int r = 0; r < 4; ++r)
#pragma unroll
        for (int tt = 0; tt < 2; ++tt) acc[r][tt] = (floatx4){0.f, 0.f, 0.f, 0.f};

#pragma unroll
    for (int kc = 0; kc < 8; ++kc) {
        int m = kc >> 2;
        short8 af[4];
#pragma unroll
        for (int r = 0; r < 4; ++r) {
            int row = r * 16 + r16;
            int slot = ((kc & 3) * 4 + q) ^ r16;       // row&15 == r16
            af[r] = *(const short8*)(smem + m * 8192 + row * 128 + slot * 8);
        }
#pragma unroll
        for (int r = 0; r < 4; ++r) {
            acc[r][0] = __builtin_amdgcn_mfma_f32_16x16x32_bf16(af[r], wf[kc][0], acc[r][0], 0, 0, 0);
            acc[r][1] = __builtin_amdgcn_mfma_f32_16x16x32_bf16(af[r], wf[kc][1], acc[r][1], 0, 0, 0);
        }
    }

#pragma unroll
    for (int tt = 0; tt < 2; ++tt) {
        int col = (wave * 2 + tt) * 16 + r16;
#pragma unroll
        for (int r = 0; r < 4; ++r)
#pragma unroll
            for (int rr = 0; rr < 4; ++rr) {
                int row = rb + r * 16 + q * 4 + rr;
                if (row < N) {
                    float v = acc[r][tt][rr] + bcol[tt];
                    if (leaky) v = v >= 0.f ? v : 0.1f * v;
                    if (resid) v += resid[(size_t)row * WW + col];
                    if (OUT_BF16)
                        ((__hip_bfloat16*)outv)[(size_t)row * WW + col] = __float2bfloat16(v);
                    else
                        ((float*)outv)[(size_t)row * WW + col] = v;
                }
            }
    }
}

extern "C" void kernel_launch(void* const* d_in, const int* in_sizes, int n_in,
                              void* d_out, int out_size, void* d_ws, size_t ws_size,
                              hipStream_t stream) {
    const float* x      = (const float*)d_in[0];
    const int*   ei     = (const int*)d_in[1];
    const float* ew     = (const float*)d_in[2];
    const int*   batch  = (const int*)d_in[3];
    const float* gnw    = (const float*)d_in[4];
    const float* gnb    = (const float*)d_in[5];
    const float* gnm    = (const float*)d_in[6];
    const float* Wrel1  = (const float*)d_in[7];
    const float* brel1  = (const float*)d_in[8];
    const float* Wroot1 = (const float*)d_in[9];
    const float* Wrel2  = (const float*)d_in[10];
    const float* brel2  = (const float*)d_in[11];
    const float* Wroot2 = (const float*)d_in[12];

    int N = in_sizes[0] / WW;
    int E = in_sizes[1] / 2;
    int P = (N + SCAN_B - 1) / SCAN_B;   // scan partial count (98 for N=100k)
    int ntiles = (N + 63) / 64;          // 64-row tiles for gemm v7

    // workspace layout (8-byte aligned):
    // aggbf | xn | y1 (bf16 N*W each) | Wb (bf16 4*W*W) | ebuf (int2 E)
    // | deg | cursor | gsum | gsumsq | gcnt | scalev | shiftv | off | bsum
    __hip_bfloat16* aggbf = (__hip_bfloat16*)d_ws;
    __hip_bfloat16* xn = aggbf + (size_t)N * WW;
    __hip_bfloat16* y1 = xn + (size_t)N * WW;
    __hip_bfloat16* Wb = y1 + (size_t)N * WW;       // [Wrel1|Wroot1|Wrel2|Wroot2]
    int2* ebuf   = (int2*)(Wb + 4 * WW * WW);
    int*  deg    = (int*)(ebuf + E);
    int*  cursor = deg + N;
    float* gsum   = (float*)(cursor + N);
    float* gsumsq = gsum + GG * WW;
    float* gcnt   = gsumsq + GG * WW;               // GG floats
    float* scalev = gcnt + GG;
    float* shiftv = scalev + GG * WW;
    int*  off    = (int*)(shiftv + GG * WW);
    int*  bsum   = off + N;

    // one memset covers deg, cursor, gsum, gsumsq, gcnt (contiguous)
    hipMemsetAsync(deg, 0, ((size_t)2 * N + 2 * GG * WW + GG) * sizeof(int), stream);

    // ---- CSR build (once; reused by both layers) ----
    hist_kernel<<<(E + 255) / 256, 256, 0, stream>>>(ei, E, deg);
    scan_blocks<<<P, SCAN_B, 0, stream>>>(deg, N, off, bsum);
    scan_partials<<<1, 256, 0, stream>>>(bsum, P);
    add_offsets<<<P, SCAN_B, 0, stream>>>(off, bsum, N);
    place_kernel<<<(E + 255) / 256, 256, 0, stream>>>(ei, ew, off, cursor, ebuf, E);

    // ---- GraphNorm ----
    cvt_w_kernel<<<(4 * WW * WW) / 256, 256, 0, stream>>>(Wrel1, Wroot1, Wrel2, Wroot2, Wb);
    stats_kernel<<<(N + 63) / 64, 128, 0, stream>>>(x, batch, N, gsum, gsumsq, gcnt);
    finalize_kernel<<<(GG * WW + 255) / 256, 256, 0, stream>>>(
        gsum, gsumsq, gcnt, gnw, gnb, gnm, scalev, shiftv);
    normalize_kernel<<<(int)(((size_t)N * (WW / 4) + 255) / 256), 256, 0, stream>>>(
        x, batch, scalev, shiftv, xn, N);

    // ---- layer 1: gather + GEMM(+bias+leaky) ----
    gather_kernel<<<(N + 3) / 4, 256, 0, stream>>>(xn, ebuf, off, deg, aggbf, N);
    gemm_kernel<true><<<ntiles, 256, 0, stream>>>(
        aggbf, xn, Wb, Wb + WW * WW, brel1, nullptr, y1, N, 1);

    // ---- layer 2: gather + GEMM(+bias+residual) ----
    gather_kernel<<<(N + 3) / 4, 256, 0, stream>>>(y1, ebuf, off, deg, aggbf, N);
    gemm_kernel<false><<<ntiles, 256, 0, stream>>>(
        aggbf, y1, Wb + 2 * WW * WW, Wb + 3 * WW * WW, brel2, x, d_out, N, 0);
}

// Round 4
// 365.050 us; speedup vs baseline: 1.2000x; 1.0196x over previous
//
#include <hip/hip_runtime.h>
#include <hip/hip_bf16.h>

#define WW 128
#define GG 64
#define GN_EPS 1e-5f
#define SCAN_B 1024

typedef __attribute__((ext_vector_type(8))) short short8;
typedef __attribute__((ext_vector_type(4))) float floatx4;

__device__ inline float bf2f(__hip_bfloat16 h) { return __bfloat162float(h); }

// ---------------- GraphNorm stats: per-graph sum, sumsq, count ----------------
__global__ __launch_bounds__(128) void stats_kernel(
    const float* __restrict__ x, const int* __restrict__ batch, int N,
    float* __restrict__ gsum, float* __restrict__ gsumsq, float* __restrict__ gcnt)
{
    int w = threadIdx.x;
    int row0 = blockIdx.x * 64;
    int row1 = min(row0 + 64, N);
    float s = 0.f, ss = 0.f;
    int cur = batch[row0];
    int cnt = 0;
    auto flush = [&]() {
        atomicAdd(&gsum[cur * WW + w], s);
        atomicAdd(&gsumsq[cur * WW + w], ss);
        if (w == 0) atomicAdd(&gcnt[cur], (float)cnt);
        s = 0.f; ss = 0.f; cnt = 0;
    };
    int i = row0;
    for (; i + 4 <= row1; i += 4) {
        int g0 = batch[i + 0], g1 = batch[i + 1], g2 = batch[i + 2], g3 = batch[i + 3];
        float v0 = x[(size_t)(i + 0) * WW + w];
        float v1 = x[(size_t)(i + 1) * WW + w];
        float v2 = x[(size_t)(i + 2) * WW + w];
        float v3 = x[(size_t)(i + 3) * WW + w];
        if (g0 != cur) { flush(); cur = g0; }
        s += v0; ss += v0 * v0; ++cnt;
        if (g1 != cur) { flush(); cur = g1; }
        s += v1; ss += v1 * v1; ++cnt;
        if (g2 != cur) { flush(); cur = g2; }
        s += v2; ss += v2 * v2; ++cnt;
        if (g3 != cur) { flush(); cur = g3; }
        s += v3; ss += v3 * v3; ++cnt;
    }
    for (; i < row1; ++i) {
        int g = batch[i];
        float v = x[(size_t)i * WW + w];
        if (g != cur) { flush(); cur = g; }
        s += v; ss += v * v; ++cnt;
    }
    flush();
}

// ---------------- fold stats into per-(g,w) affine scale/shift ----------------
__global__ __launch_bounds__(256) void finalize_kernel(
    const float* __restrict__ gsum, const float* __restrict__ gsumsq,
    const float* __restrict__ gcnt,
    const float* __restrict__ wgt, const float* __restrict__ bias,
    const float* __restrict__ ms,
    float* __restrict__ scalev, float* __restrict__ shiftv)
{
    int idx = blockIdx.x * blockDim.x + threadIdx.x;
    if (idx >= GG * WW) return;
    int g = idx >> 7, w = idx & (WW - 1);
    float cnt = gcnt[g];
    float inv = cnt > 0.f ? 1.f / cnt : 0.f;
    float mean = gsum[idx] * inv;
    float msw = ms[w];
    float var = gsumsq[idx] * inv - mean * mean * msw * (2.f - msw);
    var = fmaxf(var, 0.f);
    float sc = wgt[w] * rsqrtf(var + GN_EPS);
    scalev[idx] = sc;
    shiftv[idx] = bias[w] - sc * msw * mean;
}

// ---------------- normalize: xn = scale*x + shift (bf16 out), float4 lanes ----
__global__ __launch_bounds__(256) void normalize_kernel(
    const float* __restrict__ x, const int* __restrict__ batch,
    const float* __restrict__ scalev, const float* __restrict__ shiftv,
    __hip_bfloat16* __restrict__ xn, int N)
{
    size_t tid = (size_t)blockIdx.x * blockDim.x + threadIdx.x;   // one per 4 elems
    if (tid >= (size_t)N * (WW / 4)) return;
    int row = (int)(tid >> 5);
    int c4 = (int)(tid & 31) * 4;
    int g = batch[row];
    float4 v = *(const float4*)(x + (size_t)row * WW + c4);
    float4 sc = *(const float4*)(scalev + (size_t)g * WW + c4);
    float4 sh = *(const float4*)(shiftv + (size_t)g * WW + c4);
    __hip_bfloat162 o0, o1;
    o0.x = __float2bfloat16(sc.x * v.x + sh.x);
    o0.y = __float2bfloat16(sc.y * v.y + sh.y);
    o1.x = __float2bfloat16(sc.z * v.z + sh.z);
    o1.y = __float2bfloat16(sc.w * v.w + sh.w);
    union { __hip_bfloat162 h[2]; uint2 u; } pk;
    pk.h[0] = o0; pk.h[1] = o1;
    *(uint2*)(xn + (size_t)row * WW + c4) = pk.u;
}

// ---------------- convert fp32 weight matrices -> bf16 ----------------
__global__ __launch_bounds__(256) void cvt_w_kernel(
    const float* __restrict__ w0, const float* __restrict__ w1,
    const float* __restrict__ w2, const float* __restrict__ w3,
    __hip_bfloat16* __restrict__ dst)
{
    int idx = blockIdx.x * blockDim.x + threadIdx.x;   // 0 .. 4*16384-1
    int m = idx >> 14;
    int o = idx & 16383;
    const float* src = (m == 0) ? w0 : (m == 1) ? w1 : (m == 2) ? w2 : w3;
    dst[idx] = __float2bfloat16(src[o]);
}

// ---------------- CSR build: histogram over dst ----------------
__global__ __launch_bounds__(256) void hist_kernel(
    const int* __restrict__ ei, int E, int* __restrict__ deg)
{
    int e = blockIdx.x * 256 + threadIdx.x;
    if (e < E) atomicAdd(&deg[ei[(size_t)E + e]], 1);
}

// ---------------- hierarchical exclusive scan (3 kernels) ----------------
__global__ __launch_bounds__(SCAN_B) void scan_blocks(
    const int* __restrict__ deg, int N, int* __restrict__ off, int* __restrict__ bsum)
{
    __shared__ int s[SCAN_B];
    int t = threadIdx.x;
    int i = blockIdx.x * SCAN_B + t;
    int v = (i < N) ? deg[i] : 0;
    s[t] = v; __syncthreads();
    for (int d = 1; d < SCAN_B; d <<= 1) {
        int tmp = (t >= d) ? s[t - d] : 0;
        __syncthreads();
        s[t] += tmp;
        __syncthreads();
    }
    if (i < N) off[i] = s[t] - v;                 // block-local exclusive
    if (t == SCAN_B - 1) bsum[blockIdx.x] = s[t]; // block total
}

__global__ __launch_bounds__(256) void scan_partials(int* __restrict__ bsum, int P)
{
    __shared__ int s[256];
    int t = threadIdx.x;
    int v = (t < P) ? bsum[t] : 0;
    s[t] = v; __syncthreads();
    for (int d = 1; d < 256; d <<= 1) {
        int tmp = (t >= d) ? s[t - d] : 0;
        __syncthreads();
        s[t] += tmp;
        __syncthreads();
    }
    if (t < P) bsum[t] = s[t] - v;                // exclusive, in place
}

__global__ __launch_bounds__(SCAN_B) void add_offsets(
    int* __restrict__ off, const int* __restrict__ bsum, int N)
{
    int i = blockIdx.x * SCAN_B + threadIdx.x;
    if (i < N) off[i] += bsum[blockIdx.x];
}

// ---------------- placement v2: 4 edges/thread, batched chains ---------------
// R3 showed place at 46.6 us, 1 TB/s, WRITE_SIZE 42.8 MB (8x amplified
// scatters). 1 edge/thread = one serial load->atomic->scatter chain. v2 gives
// each thread 4 independent chains (batched dst loads, then src/w, then 4
// atomics, then 4 writes). If latency-bound this ~halves it; if flat, it's
// write-amp BW-bound (next-round signal).
__global__ __launch_bounds__(256) void place_kernel(
    const int* __restrict__ ei, const float* __restrict__ ew,
    const int* __restrict__ off, int* __restrict__ cursor,
    int2* __restrict__ ebuf, int E)
{
    int base = blockIdx.x * 1024 + threadIdx.x;
    int dstv[4], srcv[4];
    float wv[4];
    int slot[4];
#pragma unroll
    for (int i = 0; i < 4; ++i) {
        int e = base + i * 256;
        dstv[i] = (e < E) ? ei[(size_t)E + e] : -1;
    }
#pragma unroll
    for (int i = 0; i < 4; ++i) {
        int e = base + i * 256;
        if (e < E) { srcv[i] = ei[e]; wv[i] = ew[e]; }
    }
#pragma unroll
    for (int i = 0; i < 4; ++i)
        if (dstv[i] >= 0) slot[i] = off[dstv[i]] + atomicAdd(&cursor[dstv[i]], 1);
#pragma unroll
    for (int i = 0; i < 4; ++i)
        if (dstv[i] >= 0) ebuf[slot[i]] = make_int2(srcv[i], __float_as_int(wv[i]));
}

// ---------------- gather v5: masked 4-wide main loop, no serial tail ----------
__global__ __launch_bounds__(256) void gather_kernel(
    const __hip_bfloat16* __restrict__ feat, const int2* __restrict__ ebuf,
    const int* __restrict__ off, const int* __restrict__ deg,
    __hip_bfloat16* __restrict__ aggbf, int N)
{
    int wave = threadIdx.x >> 6;
    int lane = threadIdx.x & 63;
    int node = blockIdx.x * 4 + wave;
    if (node >= N) return;
    int start = off[node];
    int d = deg[node];
    const __hip_bfloat162* f2 = (const __hip_bfloat162*)feat;

    float ax0 = 0.f, ay0 = 0.f, ax1 = 0.f, ay1 = 0.f;
    float ax2 = 0.f, ay2 = 0.f, ax3 = 0.f, ay3 = 0.f;
    int last = start + d - 1;                     // d==0 -> loop skipped
    for (int k = start; k <= last; k += 4) {
        int i1 = min(k + 1, last);
        int i2 = min(k + 2, last);
        int i3 = min(k + 3, last);
        int2 p0 = ebuf[k];
        int2 p1 = ebuf[i1];
        int2 p2 = ebuf[i2];
        int2 p3 = ebuf[i3];
        __hip_bfloat162 v0 = f2[(size_t)p0.x * 64 + lane];
        __hip_bfloat162 v1 = f2[(size_t)p1.x * 64 + lane];
        __hip_bfloat162 v2 = f2[(size_t)p2.x * 64 + lane];
        __hip_bfloat162 v3 = f2[(size_t)p3.x * 64 + lane];
        float w0 = __int_as_float(p0.y);
        float w1 = (k + 1 <= last) ? __int_as_float(p1.y) : 0.f;
        float w2 = (k + 2 <= last) ? __int_as_float(p2.y) : 0.f;
        float w3 = (k + 3 <= last) ? __int_as_float(p3.y) : 0.f;
        ax0 += w0 * bf2f(v0.x); ay0 += w0 * bf2f(v0.y);
        ax1 += w1 * bf2f(v1.x); ay1 += w1 * bf2f(v1.y);
        ax2 += w2 * bf2f(v2.x); ay2 += w2 * bf2f(v2.y);
        ax3 += w3 * bf2f(v3.x); ay3 += w3 * bf2f(v3.y);
    }
    float ax = (ax0 + ax1) + (ax2 + ax3);
    float ay = (ay0 + ay1) + (ay2 + ay3);

    __hip_bfloat162 o;
    o.x = __float2bfloat16(ax);
    o.y = __float2bfloat16(ay);
    ((__hip_bfloat162*)(aggbf + (size_t)node * WW))[lane] = o;
}

// ---------------- fused GEMM v8: persistent 2-phase double-buffer ------------
// y = act([A1|A2] @ [Wrel;Wroot]^T + b) (+resid). K=256, 64-row tiles.
// v7 matched its prediction (46 us, 2.8 TB/s) but each block still serializes
// stage -> drain -> compute. v8 is the catalog's minimum 2-phase template:
// persistent grid (512 blocks = 2/CU), LDS double-buffer (2 x 32 KB), per
// tile: STAGE(buf^1, t+1) issued BEFORE compute of buf[cur]; one
// __syncthreads per tile (its vmcnt(0) drain completes the prefetch that has
// been hiding under compute+epilogue). W frags amortize over ~3 tiles.
// LDS swizzle unchanged from v7 (involution verified): slot s of row r holds
// global chunk s^(r&15); reader XORs the same.
// C/D layout: col=lane&15, row=(lane>>4)*4+reg (m89-verified).
template <bool OUT_BF16>
__global__ __launch_bounds__(256, 2) void gemm_kernel(
    const __hip_bfloat16* __restrict__ A1, const __hip_bfloat16* __restrict__ A2,
    const __hip_bfloat16* __restrict__ Wrel, const __hip_bfloat16* __restrict__ Wroot,
    const float* __restrict__ bias, const float* __restrict__ resid,
    void* __restrict__ outv, int N, int leaky, int ntiles)
{
    __shared__ __hip_bfloat16 smem[2][2 * 64 * 128];   // 2 x 32 KB
    int wave = threadIdx.x >> 6;
    int lane = threadIdx.x & 63;
    int q = lane >> 4;
    int r16 = lane & 15;

    // stage: instr t = wave*8+s covers matrix m=t>>4, rows (t&15)*4..+3.
    // lane i: row=(t&15)*4+(i>>4), fetches global chunk c=(i&15)^(row&15);
    // HW writes LDS base+i*16 (linear) -> slot d=i&15 holds chunk d^(row&15).
    auto stage = [&](int tile, int buf) {
#pragma unroll
        for (int s = 0; s < 8; ++s) {
            int t = wave * 8 + s;
            const __hip_bfloat16* Asel = (t < 16) ? A1 : A2;
            int t4 = t & 15;
            int rloc = t4 * 4 + (lane >> 4);
            int c = (lane & 15) ^ (rloc & 15);
            int grow = tile * 64 + rloc; if (grow >= N) grow = N - 1;
            const __hip_bfloat16* g = Asel + (size_t)grow * WW + c * 8;
            __hip_bfloat16* l = &smem[buf][(t >> 4) * 8192 + t4 * 512];
            __builtin_amdgcn_global_load_lds(
                (const __attribute__((address_space(1))) void*)g,
                (__attribute__((address_space(3))) void*)l, 16, 0, 0);
        }
    };

    stage(blockIdx.x, 0);

    // ---- W fragments to registers (overlap the prologue staging) ----
    short8 wf[8][2];
#pragma unroll
    for (int kc = 0; kc < 8; ++kc) {
        const __hip_bfloat16* Wsel = (kc < 4) ? Wrel : Wroot;
        int koff = (kc & 3) * 32 + q * 8;
#pragma unroll
        for (int tt = 0; tt < 2; ++tt) {
            int col = (wave * 2 + tt) * 16 + r16;
            wf[kc][tt] = *(const short8*)(Wsel + ((size_t)col * WW + koff));
        }
    }
    float bcol[2];
#pragma unroll
    for (int tt = 0; tt < 2; ++tt) bcol[tt] = bias[(wave * 2 + tt) * 16 + r16];

    __syncthreads();   // vmcnt(0) drain: first tile ready

    int cur = 0;
    for (int tile = blockIdx.x; tile < ntiles; tile += gridDim.x) {
        int nxt = tile + gridDim.x;
        if (nxt < ntiles) stage(nxt, cur ^ 1);   // prefetch hides under compute

        floatx4 acc[4][2];
#pragma unroll
        for (int r = 0; r < 4; ++r)
#pragma unroll
            for (int tt = 0; tt < 2; ++tt) acc[r][tt] = (floatx4){0.f, 0.f, 0.f, 0.f};

#pragma unroll
        for (int kc = 0; kc < 8; ++kc) {
            int m = kc >> 2;
            short8 af[4];
#pragma unroll
            for (int r = 0; r < 4; ++r) {
                int row = r * 16 + r16;
                int slot = ((kc & 3) * 4 + q) ^ r16;       // row&15 == r16
                af[r] = *(const short8*)(&smem[cur][m * 8192 + row * 128 + slot * 8]);
            }
#pragma unroll
            for (int r = 0; r < 4; ++r) {
                acc[r][0] = __builtin_amdgcn_mfma_f32_16x16x32_bf16(af[r], wf[kc][0], acc[r][0], 0, 0, 0);
                acc[r][1] = __builtin_amdgcn_mfma_f32_16x16x32_bf16(af[r], wf[kc][1], acc[r][1], 0, 0, 0);
            }
        }

        int rb = tile * 64;
#pragma unroll
        for (int tt = 0; tt < 2; ++tt) {
            int col = (wave * 2 + tt) * 16 + r16;
#pragma unroll
            for (int r = 0; r < 4; ++r)
#pragma unroll
                for (int rr = 0; rr < 4; ++rr) {
                    int row = rb + r * 16 + q * 4 + rr;
                    if (row < N) {
                        float v = acc[r][tt][rr] + bcol[tt];
                        if (leaky) v = v >= 0.f ? v : 0.1f * v;
                        if (resid) v += resid[(size_t)row * WW + col];
                        if (OUT_BF16)
                            ((__hip_bfloat16*)outv)[(size_t)row * WW + col] = __float2bfloat16(v);
                        else
                            ((float*)outv)[(size_t)row * WW + col] = v;
                    }
                }
        }

        __syncthreads();   // all reads of smem[cur] done; prefetch drained
        cur ^= 1;
    }
}

extern "C" void kernel_launch(void* const* d_in, const int* in_sizes, int n_in,
                              void* d_out, int out_size, void* d_ws, size_t ws_size,
                              hipStream_t stream) {
    const float* x      = (const float*)d_in[0];
    const int*   ei     = (const int*)d_in[1];
    const float* ew     = (const float*)d_in[2];
    const int*   batch  = (const int*)d_in[3];
    const float* gnw    = (const float*)d_in[4];
    const float* gnb    = (const float*)d_in[5];
    const float* gnm    = (const float*)d_in[6];
    const float* Wrel1  = (const float*)d_in[7];
    const float* brel1  = (const float*)d_in[8];
    const float* Wroot1 = (const float*)d_in[9];
    const float* Wrel2  = (const float*)d_in[10];
    const float* brel2  = (const float*)d_in[11];
    const float* Wroot2 = (const float*)d_in[12];

    int N = in_sizes[0] / WW;
    int E = in_sizes[1] / 2;
    int P = (N + SCAN_B - 1) / SCAN_B;   // scan partial count (98 for N=100k)
    int ntiles = (N + 63) / 64;          // 64-row tiles
    int ggrid = ntiles < 512 ? ntiles : 512;   // persistent: 2 blocks/CU

    // workspace layout (8-byte aligned):
    // aggbf | xn | y1 (bf16 N*W each) | Wb (bf16 4*W*W) | ebuf (int2 E)
    // | deg | cursor | gsum | gsumsq | gcnt | scalev | shiftv | off | bsum
    __hip_bfloat16* aggbf = (__hip_bfloat16*)d_ws;
    __hip_bfloat16* xn = aggbf + (size_t)N * WW;
    __hip_bfloat16* y1 = xn + (size_t)N * WW;
    __hip_bfloat16* Wb = y1 + (size_t)N * WW;       // [Wrel1|Wroot1|Wrel2|Wroot2]
    int2* ebuf   = (int2*)(Wb + 4 * WW * WW);
    int*  deg    = (int*)(ebuf + E);
    int*  cursor = deg + N;
    float* gsum   = (float*)(cursor + N);
    float* gsumsq = gsum + GG * WW;
    float* gcnt   = gsumsq + GG * WW;               // GG floats
    float* scalev = gcnt + GG;
    float* shiftv = scalev + GG * WW;
    int*  off    = (int*)(shiftv + GG * WW);
    int*  bsum   = off + N;

    // one memset covers deg, cursor, gsum, gsumsq, gcnt (contiguous)
    hipMemsetAsync(deg, 0, ((size_t)2 * N + 2 * GG * WW + GG) * sizeof(int), stream);

    // ---- CSR build (once; reused by both layers) ----
    hist_kernel<<<(E + 255) / 256, 256, 0, stream>>>(ei, E, deg);
    scan_blocks<<<P, SCAN_B, 0, stream>>>(deg, N, off, bsum);
    scan_partials<<<1, 256, 0, stream>>>(bsum, P);
    add_offsets<<<P, SCAN_B, 0, stream>>>(off, bsum, N);
    place_kernel<<<(E + 1023) / 1024, 256, 0, stream>>>(ei, ew, off, cursor, ebuf, E);

    // ---- GraphNorm ----
    cvt_w_kernel<<<(4 * WW * WW) / 256, 256, 0, stream>>>(Wrel1, Wroot1, Wrel2, Wroot2, Wb);
    stats_kernel<<<(N + 63) / 64, 128, 0, stream>>>(x, batch, N, gsum, gsumsq, gcnt);
    finalize_kernel<<<(GG * WW + 255) / 256, 256, 0, stream>>>(
        gsum, gsumsq, gcnt, gnw, gnb, gnm, scalev, shiftv);
    normalize_kernel<<<(int)(((size_t)N * (WW / 4) + 255) / 256), 256, 0, stream>>>(
        x, batch, scalev, shiftv, xn, N);

    // ---- layer 1: gather + GEMM(+bias+leaky) ----
    gather_kernel<<<(N + 3) / 4, 256, 0, stream>>>(xn, ebuf, off, deg, aggbf, N);
    gemm_kernel<true><<<ggrid, 256, 0, stream>>>(
        aggbf, xn, Wb, Wb + WW * WW, brel1, nullptr, y1, N, 1, ntiles);

    // ---- layer 2: gather + GEMM(+bias+residual) ----
    gather_kernel<<<(N + 3) / 4, 256, 0, stream>>>(y1, ebuf, off, deg, aggbf, N);
    gemm_kernel<false><<<ggrid, 256, 0, stream>>>(
        aggbf, y1, Wb + 2 * WW * WW, Wb + 3 * WW * WW, brel2, x, d_out, N, 0, ntiles);
}

// Round 5
// 363.595 us; speedup vs baseline: 1.2048x; 1.0040x over previous
//
#include <hip/hip_runtime.h>
#include <hip/hip_bf16.h>

#define WW 128
#define GG 64
#define GN_EPS 1e-5f
#define SCAN_B 1024

typedef __attribute__((ext_vector_type(8))) short short8;
typedef __attribute__((ext_vector_type(4))) float floatx4;

__device__ inline float bf2f(__hip_bfloat16 h) { return __bfloat162float(h); }

// ---------------- GraphNorm stats: per-graph sum, sumsq, count ----------------
__global__ __launch_bounds__(128) void stats_kernel(
    const float* __restrict__ x, const int* __restrict__ batch, int N,
    float* __restrict__ gsum, float* __restrict__ gsumsq, float* __restrict__ gcnt)
{
    int w = threadIdx.x;
    int row0 = blockIdx.x * 64;
    int row1 = min(row0 + 64, N);
    float s = 0.f, ss = 0.f;
    int cur = batch[row0];
    int cnt = 0;
    auto flush = [&]() {
        atomicAdd(&gsum[cur * WW + w], s);
        atomicAdd(&gsumsq[cur * WW + w], ss);
        if (w == 0) atomicAdd(&gcnt[cur], (float)cnt);
        s = 0.f; ss = 0.f; cnt = 0;
    };
    int i = row0;
    for (; i + 4 <= row1; i += 4) {
        int g0 = batch[i + 0], g1 = batch[i + 1], g2 = batch[i + 2], g3 = batch[i + 3];
        float v0 = x[(size_t)(i + 0) * WW + w];
        float v1 = x[(size_t)(i + 1) * WW + w];
        float v2 = x[(size_t)(i + 2) * WW + w];
        float v3 = x[(size_t)(i + 3) * WW + w];
        if (g0 != cur) { flush(); cur = g0; }
        s += v0; ss += v0 * v0; ++cnt;
        if (g1 != cur) { flush(); cur = g1; }
        s += v1; ss += v1 * v1; ++cnt;
        if (g2 != cur) { flush(); cur = g2; }
        s += v2; ss += v2 * v2; ++cnt;
        if (g3 != cur) { flush(); cur = g3; }
        s += v3; ss += v3 * v3; ++cnt;
    }
    for (; i < row1; ++i) {
        int g = batch[i];
        float v = x[(size_t)i * WW + w];
        if (g != cur) { flush(); cur = g; }
        s += v; ss += v * v; ++cnt;
    }
    flush();
}

// ---------------- fold stats into per-(g,w) affine scale/shift ----------------
__global__ __launch_bounds__(256) void finalize_kernel(
    const float* __restrict__ gsum, const float* __restrict__ gsumsq,
    const float* __restrict__ gcnt,
    const float* __restrict__ wgt, const float* __restrict__ bias,
    const float* __restrict__ ms,
    float* __restrict__ scalev, float* __restrict__ shiftv)
{
    int idx = blockIdx.x * blockDim.x + threadIdx.x;
    if (idx >= GG * WW) return;
    int g = idx >> 7, w = idx & (WW - 1);
    float cnt = gcnt[g];
    float inv = cnt > 0.f ? 1.f / cnt : 0.f;
    float mean = gsum[idx] * inv;
    float msw = ms[w];
    float var = gsumsq[idx] * inv - mean * mean * msw * (2.f - msw);
    var = fmaxf(var, 0.f);
    float sc = wgt[w] * rsqrtf(var + GN_EPS);
    scalev[idx] = sc;
    shiftv[idx] = bias[w] - sc * msw * mean;
}

// ---------------- normalize: xn = scale*x + shift (bf16 out), float4 lanes ----
__global__ __launch_bounds__(256) void normalize_kernel(
    const float* __restrict__ x, const int* __restrict__ batch,
    const float* __restrict__ scalev, const float* __restrict__ shiftv,
    __hip_bfloat16* __restrict__ xn, int N)
{
    size_t tid = (size_t)blockIdx.x * blockDim.x + threadIdx.x;   // one per 4 elems
    if (tid >= (size_t)N * (WW / 4)) return;
    int row = (int)(tid >> 5);
    int c4 = (int)(tid & 31) * 4;
    int g = batch[row];
    float4 v = *(const float4*)(x + (size_t)row * WW + c4);
    float4 sc = *(const float4*)(scalev + (size_t)g * WW + c4);
    float4 sh = *(const float4*)(shiftv + (size_t)g * WW + c4);
    __hip_bfloat162 o0, o1;
    o0.x = __float2bfloat16(sc.x * v.x + sh.x);
    o0.y = __float2bfloat16(sc.y * v.y + sh.y);
    o1.x = __float2bfloat16(sc.z * v.z + sh.z);
    o1.y = __float2bfloat16(sc.w * v.w + sh.w);
    union { __hip_bfloat162 h[2]; uint2 u; } pk;
    pk.h[0] = o0; pk.h[1] = o1;
    *(uint2*)(xn + (size_t)row * WW + c4) = pk.u;
}

// ---------------- convert fp32 weight matrices -> bf16 ----------------
__global__ __launch_bounds__(256) void cvt_w_kernel(
    const float* __restrict__ w0, const float* __restrict__ w1,
    const float* __restrict__ w2, const float* __restrict__ w3,
    __hip_bfloat16* __restrict__ dst)
{
    int idx = blockIdx.x * blockDim.x + threadIdx.x;   // 0 .. 4*16384-1
    int m = idx >> 14;
    int o = idx & 16383;
    const float* src = (m == 0) ? w0 : (m == 1) ? w1 : (m == 2) ? w2 : w3;
    dst[idx] = __float2bfloat16(src[o]);
}

// ---------------- CSR build: histogram over dst ----------------
__global__ __launch_bounds__(256) void hist_kernel(
    const int* __restrict__ ei, int E, int* __restrict__ deg)
{
    int e = blockIdx.x * 256 + threadIdx.x;
    if (e < E) atomicAdd(&deg[ei[(size_t)E + e]], 1);
}

// ---------------- hierarchical exclusive scan (3 kernels) ----------------
__global__ __launch_bounds__(SCAN_B) void scan_blocks(
    const int* __restrict__ deg, int N, int* __restrict__ off, int* __restrict__ bsum)
{
    __shared__ int s[SCAN_B];
    int t = threadIdx.x;
    int i = blockIdx.x * SCAN_B + t;
    int v = (i < N) ? deg[i] : 0;
    s[t] = v; __syncthreads();
    for (int d = 1; d < SCAN_B; d <<= 1) {
        int tmp = (t >= d) ? s[t - d] : 0;
        __syncthreads();
        s[t] += tmp;
        __syncthreads();
    }
    if (i < N) off[i] = s[t] - v;                 // block-local exclusive
    if (t == SCAN_B - 1) bsum[blockIdx.x] = s[t]; // block total
}

__global__ __launch_bounds__(256) void scan_partials(int* __restrict__ bsum, int P)
{
    __shared__ int s[256];
    int t = threadIdx.x;
    int v = (t < P) ? bsum[t] : 0;
    s[t] = v; __syncthreads();
    for (int d = 1; d < 256; d <<= 1) {
        int tmp = (t >= d) ? s[t - d] : 0;
        __syncthreads();
        s[t] += tmp;
        __syncthreads();
    }
    if (t < P) bsum[t] = s[t] - v;                // exclusive, in place
}

__global__ __launch_bounds__(SCAN_B) void add_offsets(
    int* __restrict__ off, const int* __restrict__ bsum, int N)
{
    int i = blockIdx.x * SCAN_B + threadIdx.x;
    if (i < N) off[i] += bsum[blockIdx.x];
}

// ---------------- placement v2: 4 edges/thread, batched chains ---------------
__global__ __launch_bounds__(256) void place_kernel(
    const int* __restrict__ ei, const float* __restrict__ ew,
    const int* __restrict__ off, int* __restrict__ cursor,
    int2* __restrict__ ebuf, int E)
{
    int base = blockIdx.x * 1024 + threadIdx.x;
    int dstv[4], srcv[4];
    float wv[4];
    int slot[4];
#pragma unroll
    for (int i = 0; i < 4; ++i) {
        int e = base + i * 256;
        dstv[i] = (e < E) ? ei[(size_t)E + e] : -1;
    }
#pragma unroll
    for (int i = 0; i < 4; ++i) {
        int e = base + i * 256;
        if (e < E) { srcv[i] = ei[e]; wv[i] = ew[e]; }
    }
#pragma unroll
    for (int i = 0; i < 4; ++i)
        if (dstv[i] >= 0) slot[i] = off[dstv[i]] + atomicAdd(&cursor[dstv[i]], 1);
#pragma unroll
    for (int i = 0; i < 4; ++i)
        if (dstv[i] >= 0) ebuf[slot[i]] = make_int2(srcv[i], __float_as_int(wv[i]));
}

// ---------------- gather v5: masked 4-wide main loop, no serial tail ----------
__global__ __launch_bounds__(256) void gather_kernel(
    const __hip_bfloat16* __restrict__ feat, const int2* __restrict__ ebuf,
    const int* __restrict__ off, const int* __restrict__ deg,
    __hip_bfloat16* __restrict__ aggbf, int N)
{
    int wave = threadIdx.x >> 6;
    int lane = threadIdx.x & 63;
    int node = blockIdx.x * 4 + wave;
    if (node >= N) return;
    int start = off[node];
    int d = deg[node];
    const __hip_bfloat162* f2 = (const __hip_bfloat162*)feat;

    float ax0 = 0.f, ay0 = 0.f, ax1 = 0.f, ay1 = 0.f;
    float ax2 = 0.f, ay2 = 0.f, ax3 = 0.f, ay3 = 0.f;
    int last = start + d - 1;                     // d==0 -> loop skipped
    for (int k = start; k <= last; k += 4) {
        int i1 = min(k + 1, last);
        int i2 = min(k + 2, last);
        int i3 = min(k + 3, last);
        int2 p0 = ebuf[k];
        int2 p1 = ebuf[i1];
        int2 p2 = ebuf[i2];
        int2 p3 = ebuf[i3];
        __hip_bfloat162 v0 = f2[(size_t)p0.x * 64 + lane];
        __hip_bfloat162 v1 = f2[(size_t)p1.x * 64 + lane];
        __hip_bfloat162 v2 = f2[(size_t)p2.x * 64 + lane];
        __hip_bfloat162 v3 = f2[(size_t)p3.x * 64 + lane];
        float w0 = __int_as_float(p0.y);
        float w1 = (k + 1 <= last) ? __int_as_float(p1.y) : 0.f;
        float w2 = (k + 2 <= last) ? __int_as_float(p2.y) : 0.f;
        float w3 = (k + 3 <= last) ? __int_as_float(p3.y) : 0.f;
        ax0 += w0 * bf2f(v0.x); ay0 += w0 * bf2f(v0.y);
        ax1 += w1 * bf2f(v1.x); ay1 += w1 * bf2f(v1.y);
        ax2 += w2 * bf2f(v2.x); ay2 += w2 * bf2f(v2.y);
        ax3 += w3 * bf2f(v3.x); ay3 += w3 * bf2f(v3.y);
    }
    float ax = (ax0 + ax1) + (ax2 + ax3);
    float ay = (ay0 + ay1) + (ay2 + ay3);

    __hip_bfloat162 o;
    o.x = __float2bfloat16(ax);
    o.y = __float2bfloat16(ay);
    ((__hip_bfloat162*)(aggbf + (size_t)node * WW))[lane] = o;
}

// ---------------- fused GEMM v9: 32-row tiles, dbuf @ 32 KB, balanced grid ---
// y = act([A1|A2] @ [Wrel;Wroot]^T + b) (+resid). K=256.
// R4 isolated the levers: pipeline efficiency (dur*occ 1458->885) is real but
// 64 KB LDS halved residency (occ 16.8%) and grid 512 over 1563 tiles gave a
// 3-vs-4-tile straggler tail. v9 keeps the identical 2-phase schedule with
// 16 KB buffers (32-row tile, both matrices) -> 32 KB total like v7, and a
// balanced persistent grid ceil(ntiles/3) so every block runs ~exactly 3
// tiles. Predicted by the dur*occ law: ~27-33 us at 28-38% occupancy.
// LDS swizzle (involution, conflict-free, 0 measured): slot s of row r holds
// global chunk s^(r&15); reader XORs the same.
// C/D layout: col=lane&15, row=(lane>>4)*4+reg (m89-verified).
template <bool OUT_BF16>
__global__ __launch_bounds__(256, 4) void gemm_kernel(
    const __hip_bfloat16* __restrict__ A1, const __hip_bfloat16* __restrict__ A2,
    const __hip_bfloat16* __restrict__ Wrel, const __hip_bfloat16* __restrict__ Wroot,
    const float* __restrict__ bias, const float* __restrict__ resid,
    void* __restrict__ outv, int N, int leaky, int ntiles)
{
    __shared__ __hip_bfloat16 smem[2][2 * 32 * 128];   // 2 x 16 KB
    int wave = threadIdx.x >> 6;
    int lane = threadIdx.x & 63;
    int q = lane >> 4;
    int r16 = lane & 15;

    // stage one 32-row tile (A1+A2, 16 KB): instr t = wave*4+s, t in 0..15;
    // matrix m = t>>3, rows (t&7)*4..+3. lane i: row=(t&7)*4+(i>>4), fetches
    // global chunk c=(i&15)^(row&15); HW writes LDS base+i*16 (linear) ->
    // slot d=i&15 holds chunk d^(row&15).
    auto stage = [&](int tile, int buf) {
#pragma unroll
        for (int s = 0; s < 4; ++s) {
            int t = wave * 4 + s;
            const __hip_bfloat16* Asel = (t < 8) ? A1 : A2;
            int t8 = t & 7;
            int rloc = t8 * 4 + (lane >> 4);
            int c = (lane & 15) ^ (rloc & 15);
            int grow = tile * 32 + rloc; if (grow >= N) grow = N - 1;
            const __hip_bfloat16* g = Asel + (size_t)grow * WW + c * 8;
            __hip_bfloat16* l = &smem[buf][(t >> 3) * 4096 + t8 * 512];
            __builtin_amdgcn_global_load_lds(
                (const __attribute__((address_space(1))) void*)g,
                (__attribute__((address_space(3))) void*)l, 16, 0, 0);
        }
    };

    stage(blockIdx.x, 0);

    // ---- W fragments to registers (overlap the prologue staging) ----
    short8 wf[8][2];
#pragma unroll
    for (int kc = 0; kc < 8; ++kc) {
        const __hip_bfloat16* Wsel = (kc < 4) ? Wrel : Wroot;
        int koff = (kc & 3) * 32 + q * 8;
#pragma unroll
        for (int tt = 0; tt < 2; ++tt) {
            int col = (wave * 2 + tt) * 16 + r16;
            wf[kc][tt] = *(const short8*)(Wsel + ((size_t)col * WW + koff));
        }
    }
    float bcol[2];
#pragma unroll
    for (int tt = 0; tt < 2; ++tt) bcol[tt] = bias[(wave * 2 + tt) * 16 + r16];

    __syncthreads();   // vmcnt(0) drain: first tile ready

    int cur = 0;
    for (int tile = blockIdx.x; tile < ntiles; tile += gridDim.x) {
        int nxt = tile + gridDim.x;
        if (nxt < ntiles) stage(nxt, cur ^ 1);   // prefetch hides under compute

        floatx4 acc[2][2];
#pragma unroll
        for (int r = 0; r < 2; ++r)
#pragma unroll
            for (int tt = 0; tt < 2; ++tt) acc[r][tt] = (floatx4){0.f, 0.f, 0.f, 0.f};

#pragma unroll
        for (int kc = 0; kc < 8; ++kc) {
            int m = kc >> 2;
            short8 af[2];
#pragma unroll
            for (int r = 0; r < 2; ++r) {
                int row = r * 16 + r16;
                int slot = ((kc & 3) * 4 + q) ^ r16;       // row&15 == r16
                af[r] = *(const short8*)(&smem[cur][m * 4096 + row * 128 + slot * 8]);
            }
#pragma unroll
            for (int r = 0; r < 2; ++r) {
                acc[r][0] = __builtin_amdgcn_mfma_f32_16x16x32_bf16(af[r], wf[kc][0], acc[r][0], 0, 0, 0);
                acc[r][1] = __builtin_amdgcn_mfma_f32_16x16x32_bf16(af[r], wf[kc][1], acc[r][1], 0, 0, 0);
            }
        }

        int rb = tile * 32;
#pragma unroll
        for (int tt = 0; tt < 2; ++tt) {
            int col = (wave * 2 + tt) * 16 + r16;
#pragma unroll
            for (int r = 0; r < 2; ++r)
#pragma unroll
                for (int rr = 0; rr < 4; ++rr) {
                    int row = rb + r * 16 + q * 4 + rr;
                    if (row < N) {
                        float v = acc[r][tt][rr] + bcol[tt];
                        if (leaky) v = v >= 0.f ? v : 0.1f * v;
                        if (resid) v += resid[(size_t)row * WW + col];
                        if (OUT_BF16)
                            ((__hip_bfloat16*)outv)[(size_t)row * WW + col] = __float2bfloat16(v);
                        else
                            ((float*)outv)[(size_t)row * WW + col] = v;
                    }
                }
        }

        __syncthreads();   // all reads of smem[cur] done; prefetch drained
        cur ^= 1;
    }
}

extern "C" void kernel_launch(void* const* d_in, const int* in_sizes, int n_in,
                              void* d_out, int out_size, void* d_ws, size_t ws_size,
                              hipStream_t stream) {
    const float* x      = (const float*)d_in[0];
    const int*   ei     = (const int*)d_in[1];
    const float* ew     = (const float*)d_in[2];
    const int*   batch  = (const int*)d_in[3];
    const float* gnw    = (const float*)d_in[4];
    const float* gnb    = (const float*)d_in[5];
    const float* gnm    = (const float*)d_in[6];
    const float* Wrel1  = (const float*)d_in[7];
    const float* brel1  = (const float*)d_in[8];
    const float* Wroot1 = (const float*)d_in[9];
    const float* Wrel2  = (const float*)d_in[10];
    const float* brel2  = (const float*)d_in[11];
    const float* Wroot2 = (const float*)d_in[12];

    int N = in_sizes[0] / WW;
    int E = in_sizes[1] / 2;
    int P = (N + SCAN_B - 1) / SCAN_B;   // scan partial count (98 for N=100k)
    int ntiles = (N + 31) / 32;          // 32-row tiles for gemm v9 (3125)
    int ggrid = (ntiles + 2) / 3;        // balanced: ~every block gets 3 tiles

    // workspace layout (8-byte aligned):
    // aggbf | xn | y1 (bf16 N*W each) | Wb (bf16 4*W*W) | ebuf (int2 E)
    // | deg | cursor | gsum | gsumsq | gcnt | scalev | shiftv | off | bsum
    __hip_bfloat16* aggbf = (__hip_bfloat16*)d_ws;
    __hip_bfloat16* xn = aggbf + (size_t)N * WW;
    __hip_bfloat16* y1 = xn + (size_t)N * WW;
    __hip_bfloat16* Wb = y1 + (size_t)N * WW;       // [Wrel1|Wroot1|Wrel2|Wroot2]
    int2* ebuf   = (int2*)(Wb + 4 * WW * WW);
    int*  deg    = (int*)(ebuf + E);
    int*  cursor = deg + N;
    float* gsum   = (float*)(cursor + N);
    float* gsumsq = gsum + GG * WW;
    float* gcnt   = gsumsq + GG * WW;               // GG floats
    float* scalev = gcnt + GG;
    float* shiftv = scalev + GG * WW;
    int*  off    = (int*)(shiftv + GG * WW);
    int*  bsum   = off + N;

    // one memset covers deg, cursor, gsum, gsumsq, gcnt (contiguous)
    hipMemsetAsync(deg, 0, ((size_t)2 * N + 2 * GG * WW + GG) * sizeof(int), stream);

    // ---- CSR build (once; reused by both layers) ----
    hist_kernel<<<(E + 255) / 256, 256, 0, stream>>>(ei, E, deg);
    scan_blocks<<<P, SCAN_B, 0, stream>>>(deg, N, off, bsum);
    scan_partials<<<1, 256, 0, stream>>>(bsum, P);
    add_offsets<<<P, SCAN_B, 0, stream>>>(off, bsum, N);
    place_kernel<<<(E + 1023) / 1024, 256, 0, stream>>>(ei, ew, off, cursor, ebuf, E);

    // ---- GraphNorm ----
    cvt_w_kernel<<<(4 * WW * WW) / 256, 256, 0, stream>>>(Wrel1, Wroot1, Wrel2, Wroot2, Wb);
    stats_kernel<<<(N + 63) / 64, 128, 0, stream>>>(x, batch, N, gsum, gsumsq, gcnt);
    finalize_kernel<<<(GG * WW + 255) / 256, 256, 0, stream>>>(
        gsum, gsumsq, gcnt, gnw, gnb, gnm, scalev, shiftv);
    normalize_kernel<<<(int)(((size_t)N * (WW / 4) + 255) / 256), 256, 0, stream>>>(
        x, batch, scalev, shiftv, xn, N);

    // ---- layer 1: gather + GEMM(+bias+leaky) ----
    gather_kernel<<<(N + 3) / 4, 256, 0, stream>>>(xn, ebuf, off, deg, aggbf, N);
    gemm_kernel<true><<<ggrid, 256, 0, stream>>>(
        aggbf, xn, Wb, Wb + WW * WW, brel1, nullptr, y1, N, 1, ntiles);

    // ---- layer 2: gather + GEMM(+bias+residual) ----
    gather_kernel<<<(N + 3) / 4, 256, 0, stream>>>(y1, ebuf, off, deg, aggbf, N);
    gemm_kernel<false><<<ggrid, 256, 0, stream>>>(
        aggbf, y1, Wb + 2 * WW * WW, Wb + 3 * WW * WW, brel2, x, d_out, N, 0, ntiles);
}

// Round 6
// 327.539 us; speedup vs baseline: 1.3374x; 1.1101x over previous
//
#include <hip/hip_runtime.h>
#include <hip/hip_bf16.h>

#define WW 128
#define GG 64
#define GN_EPS 1e-5f
#define SCAN_B 1024

typedef __attribute__((ext_vector_type(8))) short short8;
typedef __attribute__((ext_vector_type(4))) float floatx4;

__device__ inline float bf2f(__hip_bfloat16 h) { return __bfloat162float(h); }
__device__ inline float bfbits2f(short v) {
    return __uint_as_float(((unsigned)(unsigned short)v) << 16);
}
__device__ inline short f2bfbits(float f) {
    __hip_bfloat16 h = __float2bfloat16(f);
    return *reinterpret_cast<short*>(&h);
}

// ---------------- GraphNorm stats: per-graph sum, sumsq, count ----------------
__global__ __launch_bounds__(128) void stats_kernel(
    const float* __restrict__ x, const int* __restrict__ batch, int N,
    float* __restrict__ gsum, float* __restrict__ gsumsq, float* __restrict__ gcnt)
{
    int w = threadIdx.x;
    int row0 = blockIdx.x * 64;
    int row1 = min(row0 + 64, N);
    float s = 0.f, ss = 0.f;
    int cur = batch[row0];
    int cnt = 0;
    auto flush = [&]() {
        atomicAdd(&gsum[cur * WW + w], s);
        atomicAdd(&gsumsq[cur * WW + w], ss);
        if (w == 0) atomicAdd(&gcnt[cur], (float)cnt);
        s = 0.f; ss = 0.f; cnt = 0;
    };
    int i = row0;
    for (; i + 4 <= row1; i += 4) {
        int g0 = batch[i + 0], g1 = batch[i + 1], g2 = batch[i + 2], g3 = batch[i + 3];
        float v0 = x[(size_t)(i + 0) * WW + w];
        float v1 = x[(size_t)(i + 1) * WW + w];
        float v2 = x[(size_t)(i + 2) * WW + w];
        float v3 = x[(size_t)(i + 3) * WW + w];
        if (g0 != cur) { flush(); cur = g0; }
        s += v0; ss += v0 * v0; ++cnt;
        if (g1 != cur) { flush(); cur = g1; }
        s += v1; ss += v1 * v1; ++cnt;
        if (g2 != cur) { flush(); cur = g2; }
        s += v2; ss += v2 * v2; ++cnt;
        if (g3 != cur) { flush(); cur = g3; }
        s += v3; ss += v3 * v3; ++cnt;
    }
    for (; i < row1; ++i) {
        int g = batch[i];
        float v = x[(size_t)i * WW + w];
        if (g != cur) { flush(); cur = g; }
        s += v; ss += v * v; ++cnt;
    }
    flush();
}

// ---------------- fold stats into per-(g,w) affine scale/shift ----------------
__global__ __launch_bounds__(256) void finalize_kernel(
    const float* __restrict__ gsum, const float* __restrict__ gsumsq,
    const float* __restrict__ gcnt,
    const float* __restrict__ wgt, const float* __restrict__ bias,
    const float* __restrict__ ms,
    float* __restrict__ scalev, float* __restrict__ shiftv)
{
    int idx = blockIdx.x * blockDim.x + threadIdx.x;
    if (idx >= GG * WW) return;
    int g = idx >> 7, w = idx & (WW - 1);
    float cnt = gcnt[g];
    float inv = cnt > 0.f ? 1.f / cnt : 0.f;
    float mean = gsum[idx] * inv;
    float msw = ms[w];
    float var = gsumsq[idx] * inv - mean * mean * msw * (2.f - msw);
    var = fmaxf(var, 0.f);
    float sc = wgt[w] * rsqrtf(var + GN_EPS);
    scalev[idx] = sc;
    shiftv[idx] = bias[w] - sc * msw * mean;
}

// ---------------- normalize: xn = scale*x + shift (bf16 out), float4 lanes ----
__global__ __launch_bounds__(256) void normalize_kernel(
    const float* __restrict__ x, const int* __restrict__ batch,
    const float* __restrict__ scalev, const float* __restrict__ shiftv,
    __hip_bfloat16* __restrict__ xn, int N)
{
    size_t tid = (size_t)blockIdx.x * blockDim.x + threadIdx.x;   // one per 4 elems
    if (tid >= (size_t)N * (WW / 4)) return;
    int row = (int)(tid >> 5);
    int c4 = (int)(tid & 31) * 4;
    int g = batch[row];
    float4 v = *(const float4*)(x + (size_t)row * WW + c4);
    float4 sc = *(const float4*)(scalev + (size_t)g * WW + c4);
    float4 sh = *(const float4*)(shiftv + (size_t)g * WW + c4);
    __hip_bfloat162 o0, o1;
    o0.x = __float2bfloat16(sc.x * v.x + sh.x);
    o0.y = __float2bfloat16(sc.y * v.y + sh.y);
    o1.x = __float2bfloat16(sc.z * v.z + sh.z);
    o1.y = __float2bfloat16(sc.w * v.w + sh.w);
    union { __hip_bfloat162 h[2]; uint2 u; } pk;
    pk.h[0] = o0; pk.h[1] = o1;
    *(uint2*)(xn + (size_t)row * WW + c4) = pk.u;
}

// ---------------- convert fp32 weight matrices -> bf16 ----------------
__global__ __launch_bounds__(256) void cvt_w_kernel(
    const float* __restrict__ w0, const float* __restrict__ w1,
    const float* __restrict__ w2, const float* __restrict__ w3,
    __hip_bfloat16* __restrict__ dst)
{
    int idx = blockIdx.x * blockDim.x + threadIdx.x;   // 0 .. 4*16384-1
    int m = idx >> 14;
    int o = idx & 16383;
    const float* src = (m == 0) ? w0 : (m == 1) ? w1 : (m == 2) ? w2 : w3;
    dst[idx] = __float2bfloat16(src[o]);
}

// ---------------- CSR build: histogram over dst ----------------
__global__ __launch_bounds__(256) void hist_kernel(
    const int* __restrict__ ei, int E, int* __restrict__ deg)
{
    int e = blockIdx.x * 256 + threadIdx.x;
    if (e < E) atomicAdd(&deg[ei[(size_t)E + e]], 1);
}

// ---------------- hierarchical exclusive scan (3 kernels) ----------------
__global__ __launch_bounds__(SCAN_B) void scan_blocks(
    const int* __restrict__ deg, int N, int* __restrict__ off, int* __restrict__ bsum)
{
    __shared__ int s[SCAN_B];
    int t = threadIdx.x;
    int i = blockIdx.x * SCAN_B + t;
    int v = (i < N) ? deg[i] : 0;
    s[t] = v; __syncthreads();
    for (int d = 1; d < SCAN_B; d <<= 1) {
        int tmp = (t >= d) ? s[t - d] : 0;
        __syncthreads();
        s[t] += tmp;
        __syncthreads();
    }
    if (i < N) off[i] = s[t] - v;                 // block-local exclusive
    if (t == SCAN_B - 1) bsum[blockIdx.x] = s[t]; // block total
}

__global__ __launch_bounds__(256) void scan_partials(int* __restrict__ bsum, int P)
{
    __shared__ int s[256];
    int t = threadIdx.x;
    int v = (t < P) ? bsum[t] : 0;
    s[t] = v; __syncthreads();
    for (int d = 1; d < 256; d <<= 1) {
        int tmp = (t >= d) ? s[t - d] : 0;
        __syncthreads();
        s[t] += tmp;
        __syncthreads();
    }
    if (t < P) bsum[t] = s[t] - v;                // exclusive, in place
}

__global__ __launch_bounds__(SCAN_B) void add_offsets(
    int* __restrict__ off, const int* __restrict__ bsum, int N)
{
    int i = blockIdx.x * SCAN_B + threadIdx.x;
    if (i < N) off[i] += bsum[blockIdx.x];
}

// ---------------- placement v2: 4 edges/thread, batched chains ---------------
__global__ __launch_bounds__(256) void place_kernel(
    const int* __restrict__ ei, const float* __restrict__ ew,
    const int* __restrict__ off, int* __restrict__ cursor,
    int2* __restrict__ ebuf, int E)
{
    int base = blockIdx.x * 1024 + threadIdx.x;
    int dstv[4], srcv[4];
    float wv[4];
    int slot[4];
#pragma unroll
    for (int i = 0; i < 4; ++i) {
        int e = base + i * 256;
        dstv[i] = (e < E) ? ei[(size_t)E + e] : -1;
    }
#pragma unroll
    for (int i = 0; i < 4; ++i) {
        int e = base + i * 256;
        if (e < E) { srcv[i] = ei[e]; wv[i] = ew[e]; }
    }
#pragma unroll
    for (int i = 0; i < 4; ++i)
        if (dstv[i] >= 0) slot[i] = off[dstv[i]] + atomicAdd(&cursor[dstv[i]], 1);
#pragma unroll
    for (int i = 0; i < 4; ++i)
        if (dstv[i] >= 0) ebuf[slot[i]] = make_int2(srcv[i], __float_as_int(wv[i]));
}

// ---------------- fused gather+GEMM v10 ----------------
// Per 32-row tile: (1) async A2 staging of X rows via global_load_lds,
// (2) in-block gather: thread t owns node tid>>3, cols (tid&7)*16..+15; each
// edge read as 2x16B coalesced chunks (8 threads cover the full 256B row);
// fp32 accumulate (same math as old gather, 2-wide masked loop),
// (3) ds_write agg into swizzled A1 region, (4) barrier, (5) v9's MFMA loop.
// Eliminates both gather launches and the 51.2MB aggbf round-trip; scattered
// gather latency overlaps other blocks' MFMA (4 blocks/CU).
// Epilogue: W cols remapped to adjacent pairs (col = wave*32 + 2*r16 + tt) so
// stores are packed bf16x2 / float2 -> 64/128B contiguous per 16-lane group
// (fixes layer-1's 2x WRITE amplification from 32B scalar-store segments).
// LDS swizzle (involution): slot s of row r holds chunk s^(r&15); writers
// (gather ds_write + pre-swizzled global src for A2) and reader XOR the same.
// C/D layout: col=lane&15, row=(lane>>4)*4+reg (m89-verified).
template <bool OUT_BF16>
__global__ __launch_bounds__(256, 4) void fused_kernel(
    const __hip_bfloat16* __restrict__ X,
    const int2* __restrict__ ebuf, const int* __restrict__ off,
    const int* __restrict__ deg,
    const __hip_bfloat16* __restrict__ Wrel, const __hip_bfloat16* __restrict__ Wroot,
    const float* __restrict__ bias, const float* __restrict__ resid,
    void* __restrict__ outv, int N, int leaky)
{
    __shared__ __hip_bfloat16 smem[2 * 32 * 128];   // 16 KB: [A1 agg | A2 X]
    int tid = threadIdx.x;
    int wave = tid >> 6, lane = tid & 63;
    int q = lane >> 4, r16 = lane & 15;
    int rb = blockIdx.x * 32;

    // ---- (1) A2 staging: 8 x 1KB instructions, 2 per wave (async) ----
#pragma unroll
    for (int s = 0; s < 2; ++s) {
        int t = wave * 2 + s;                     // 0..7, rows t*4..t*4+3
        int rloc = t * 4 + (lane >> 4);
        int c = (lane & 15) ^ (rloc & 15);        // pre-swizzled global chunk
        int grow = rb + rloc; if (grow >= N) grow = N - 1;
        const __hip_bfloat16* g = X + (size_t)grow * WW + c * 8;
        __hip_bfloat16* l = smem + 4096 + t * 512;   // linear LDS dest
        __builtin_amdgcn_global_load_lds(
            (const __attribute__((address_space(1))) void*)g,
            (__attribute__((address_space(3))) void*)l, 16, 0, 0);
    }

    // ---- (2) gather: node = rb + tid>>3, cols (tid&7)*16..+15 ----
    int node = rb + (tid >> 3);
    int nc = node < N ? node : N - 1;
    int start = off[nc];
    int d = (node < N) ? deg[nc] : 0;
    int sub = tid & 7;
    float a16[16];
#pragma unroll
    for (int j = 0; j < 16; ++j) a16[j] = 0.f;
    int last = start + d - 1;                     // d==0 -> loop skipped
    for (int k = start; k <= last; k += 2) {
        int i1 = min(k + 1, last);
        int2 p0 = ebuf[k];
        int2 p1 = ebuf[i1];
        const __hip_bfloat16* r0 = X + (size_t)p0.x * WW + sub * 16;
        const __hip_bfloat16* r1 = X + (size_t)p1.x * WW + sub * 16;
        short8 a0 = *(const short8*)(r0);
        short8 b0 = *(const short8*)(r0 + 8);
        short8 a1 = *(const short8*)(r1);
        short8 b1 = *(const short8*)(r1 + 8);
        float w0 = __int_as_float(p0.y);
        float w1 = (k + 1 <= last) ? __int_as_float(p1.y) : 0.f;
#pragma unroll
        for (int j = 0; j < 8; ++j) {
            a16[j]     += w0 * bfbits2f(a0[j]) + w1 * bfbits2f(a1[j]);
            a16[8 + j] += w0 * bfbits2f(b0[j]) + w1 * bfbits2f(b1[j]);
        }
    }

    // ---- (3) agg -> A1 LDS region, swizzled (chunks 2*sub, 2*sub+1) ----
    {
        int r = tid >> 3;                          // local row 0..31
        short8 pk0, pk1;
#pragma unroll
        for (int j = 0; j < 8; ++j) {
            pk0[j] = f2bfbits(a16[j]);
            pk1[j] = f2bfbits(a16[8 + j]);
        }
        int s0 = (2 * sub)     ^ (r & 15);
        int s1 = (2 * sub + 1) ^ (r & 15);
        *(short8*)(smem + r * 128 + s0 * 8) = pk0;
        *(short8*)(smem + r * 128 + s1 * 8) = pk1;
    }

    // ---- W fragments: adjacent-pair cols (wave*32 + 2*r16 + tt) ----
    short8 wf[8][2];
#pragma unroll
    for (int kc = 0; kc < 8; ++kc) {
        const __hip_bfloat16* Wsel = (kc < 4) ? Wrel : Wroot;
        int koff = (kc & 3) * 32 + q * 8;
#pragma unroll
        for (int tt = 0; tt < 2; ++tt) {
            int col = wave * 32 + 2 * r16 + tt;
            wf[kc][tt] = *(const short8*)(Wsel + ((size_t)col * WW + koff));
        }
    }
    float bcol[2];
#pragma unroll
    for (int tt = 0; tt < 2; ++tt) bcol[tt] = bias[wave * 32 + 2 * r16 + tt];

    __syncthreads();   // drains vmcnt (A2 staged) + lgkm (A1 written)

    // ---- (5) MFMA: kc<4 A1*Wrel, kc>=4 A2*Wroot ----
    floatx4 acc[2][2];
#pragma unroll
    for (int r = 0; r < 2; ++r)
#pragma unroll
        for (int tt = 0; tt < 2; ++tt) acc[r][tt] = (floatx4){0.f, 0.f, 0.f, 0.f};

#pragma unroll
    for (int kc = 0; kc < 8; ++kc) {
        int m = kc >> 2;
        short8 af[2];
#pragma unroll
        for (int r = 0; r < 2; ++r) {
            int row = r * 16 + r16;
            int slot = ((kc & 3) * 4 + q) ^ r16;       // row&15 == r16
            af[r] = *(const short8*)(&smem[m * 4096 + row * 128 + slot * 8]);
        }
#pragma unroll
        for (int r = 0; r < 2; ++r) {
            acc[r][0] = __builtin_amdgcn_mfma_f32_16x16x32_bf16(af[r], wf[kc][0], acc[r][0], 0, 0, 0);
            acc[r][1] = __builtin_amdgcn_mfma_f32_16x16x32_bf16(af[r], wf[kc][1], acc[r][1], 0, 0, 0);
        }
    }

    // ---- epilogue: packed adjacent-col stores ----
    int colb = wave * 32 + 2 * r16;
#pragma unroll
    for (int r = 0; r < 2; ++r)
#pragma unroll
        for (int rr = 0; rr < 4; ++rr) {
            int row = rb + r * 16 + q * 4 + rr;
            if (row < N) {
                float v0 = acc[r][0][rr] + bcol[0];
                float v1 = acc[r][1][rr] + bcol[1];
                if (leaky) {
                    v0 = v0 >= 0.f ? v0 : 0.1f * v0;
                    v1 = v1 >= 0.f ? v1 : 0.1f * v1;
                }
                if (OUT_BF16) {
                    __hip_bfloat162 o;
                    o.x = __float2bfloat16(v0);
                    o.y = __float2bfloat16(v1);
                    *(__hip_bfloat162*)((__hip_bfloat16*)outv + (size_t)row * WW + colb) = o;
                } else {
                    float2 rv = *(const float2*)(resid + (size_t)row * WW + colb);
                    float2 o;
                    o.x = v0 + rv.x;
                    o.y = v1 + rv.y;
                    *(float2*)((float*)outv + (size_t)row * WW + colb) = o;
                }
            }
        }
}

extern "C" void kernel_launch(void* const* d_in, const int* in_sizes, int n_in,
                              void* d_out, int out_size, void* d_ws, size_t ws_size,
                              hipStream_t stream) {
    const float* x      = (const float*)d_in[0];
    const int*   ei     = (const int*)d_in[1];
    const float* ew     = (const float*)d_in[2];
    const int*   batch  = (const int*)d_in[3];
    const float* gnw    = (const float*)d_in[4];
    const float* gnb    = (const float*)d_in[5];
    const float* gnm    = (const float*)d_in[6];
    const float* Wrel1  = (const float*)d_in[7];
    const float* brel1  = (const float*)d_in[8];
    const float* Wroot1 = (const float*)d_in[9];
    const float* Wrel2  = (const float*)d_in[10];
    const float* brel2  = (const float*)d_in[11];
    const float* Wroot2 = (const float*)d_in[12];

    int N = in_sizes[0] / WW;
    int E = in_sizes[1] / 2;
    int P = (N + SCAN_B - 1) / SCAN_B;   // scan partial count (98 for N=100k)
    int ntiles = (N + 31) / 32;          // 32-row tiles (3125)

    // workspace layout (8-byte aligned):
    // xn | y1 (bf16 N*W each) | Wb (bf16 4*W*W) | ebuf (int2 E)
    // | deg | cursor | gsum | gsumsq | gcnt | scalev | shiftv | off | bsum
    __hip_bfloat16* xn = (__hip_bfloat16*)d_ws;
    __hip_bfloat16* y1 = xn + (size_t)N * WW;
    __hip_bfloat16* Wb = y1 + (size_t)N * WW;       // [Wrel1|Wroot1|Wrel2|Wroot2]
    int2* ebuf   = (int2*)(Wb + 4 * WW * WW);
    int*  deg    = (int*)(ebuf + E);
    int*  cursor = deg + N;
    float* gsum   = (float*)(cursor + N);
    float* gsumsq = gsum + GG * WW;
    float* gcnt   = gsumsq + GG * WW;               // GG floats
    float* scalev = gcnt + GG;
    float* shiftv = scalev + GG * WW;
    int*  off    = (int*)(shiftv + GG * WW);
    int*  bsum   = off + N;

    // one memset covers deg, cursor, gsum, gsumsq, gcnt (contiguous)
    hipMemsetAsync(deg, 0, ((size_t)2 * N + 2 * GG * WW + GG) * sizeof(int), stream);

    // ---- CSR build (once; reused by both layers) ----
    hist_kernel<<<(E + 255) / 256, 256, 0, stream>>>(ei, E, deg);
    scan_blocks<<<P, SCAN_B, 0, stream>>>(deg, N, off, bsum);
    scan_partials<<<1, 256, 0, stream>>>(bsum, P);
    add_offsets<<<P, SCAN_B, 0, stream>>>(off, bsum, N);
    place_kernel<<<(E + 1023) / 1024, 256, 0, stream>>>(ei, ew, off, cursor, ebuf, E);

    // ---- GraphNorm ----
    cvt_w_kernel<<<(4 * WW * WW) / 256, 256, 0, stream>>>(Wrel1, Wroot1, Wrel2, Wroot2, Wb);
    stats_kernel<<<(N + 63) / 64, 128, 0, stream>>>(x, batch, N, gsum, gsumsq, gcnt);
    finalize_kernel<<<(GG * WW + 255) / 256, 256, 0, stream>>>(
        gsum, gsumsq, gcnt, gnw, gnb, gnm, scalev, shiftv);
    normalize_kernel<<<(int)(((size_t)N * (WW / 4) + 255) / 256), 256, 0, stream>>>(
        x, batch, scalev, shiftv, xn, N);

    // ---- layer 1: fused gather+GEMM (+bias+leaky) ----
    fused_kernel<true><<<ntiles, 256, 0, stream>>>(
        xn, ebuf, off, deg, Wb, Wb + WW * WW, brel1, nullptr, y1, N, 1);

    // ---- layer 2: fused gather+GEMM (+bias+residual) ----
    fused_kernel<false><<<ntiles, 256, 0, stream>>>(
        y1, ebuf, off, deg, Wb + 2 * WW * WW, Wb + 3 * WW * WW, brel2, x, d_out, N, 0);
}

// Round 7
// 323.953 us; speedup vs baseline: 1.3522x; 1.0111x over previous
//
#include <hip/hip_runtime.h>
#include <hip/hip_bf16.h>

#define WW 128
#define GG 64
#define GN_EPS 1e-5f
#define SCAN_B 1024

typedef __attribute__((ext_vector_type(8))) short short8;
typedef __attribute__((ext_vector_type(4))) float floatx4;

__device__ inline float bf2f(__hip_bfloat16 h) { return __bfloat162float(h); }
__device__ inline float bfbits2f(short v) {
    return __uint_as_float(((unsigned)(unsigned short)v) << 16);
}
__device__ inline short f2bfbits(float f) {
    __hip_bfloat16 h = __float2bfloat16(f);
    return *reinterpret_cast<short*>(&h);
}

// ---------------- GraphNorm stats: per-graph sum, sumsq, count ----------------
// v3: 32 rows/block (was 64) -> halves the serial per-block chain; boundary
// flush logic unchanged (graph boundaries rare).
__global__ __launch_bounds__(128) void stats_kernel(
    const float* __restrict__ x, const int* __restrict__ batch, int N,
    float* __restrict__ gsum, float* __restrict__ gsumsq, float* __restrict__ gcnt)
{
    int w = threadIdx.x;
    int row0 = blockIdx.x * 32;
    int row1 = min(row0 + 32, N);
    float s = 0.f, ss = 0.f;
    int cur = batch[row0];
    int cnt = 0;
    auto flush = [&]() {
        atomicAdd(&gsum[cur * WW + w], s);
        atomicAdd(&gsumsq[cur * WW + w], ss);
        if (w == 0) atomicAdd(&gcnt[cur], (float)cnt);
        s = 0.f; ss = 0.f; cnt = 0;
    };
    int i = row0;
    for (; i + 4 <= row1; i += 4) {
        int g0 = batch[i + 0], g1 = batch[i + 1], g2 = batch[i + 2], g3 = batch[i + 3];
        float v0 = x[(size_t)(i + 0) * WW + w];
        float v1 = x[(size_t)(i + 1) * WW + w];
        float v2 = x[(size_t)(i + 2) * WW + w];
        float v3 = x[(size_t)(i + 3) * WW + w];
        if (g0 != cur) { flush(); cur = g0; }
        s += v0; ss += v0 * v0; ++cnt;
        if (g1 != cur) { flush(); cur = g1; }
        s += v1; ss += v1 * v1; ++cnt;
        if (g2 != cur) { flush(); cur = g2; }
        s += v2; ss += v2 * v2; ++cnt;
        if (g3 != cur) { flush(); cur = g3; }
        s += v3; ss += v3 * v3; ++cnt;
    }
    for (; i < row1; ++i) {
        int g = batch[i];
        float v = x[(size_t)i * WW + w];
        if (g != cur) { flush(); cur = g; }
        s += v; ss += v * v; ++cnt;
    }
    flush();
}

// ---------------- fold stats into per-(g,w) affine scale/shift ----------------
__global__ __launch_bounds__(256) void finalize_kernel(
    const float* __restrict__ gsum, const float* __restrict__ gsumsq,
    const float* __restrict__ gcnt,
    const float* __restrict__ wgt, const float* __restrict__ bias,
    const float* __restrict__ ms,
    float* __restrict__ scalev, float* __restrict__ shiftv)
{
    int idx = blockIdx.x * blockDim.x + threadIdx.x;
    if (idx >= GG * WW) return;
    int g = idx >> 7, w = idx & (WW - 1);
    float cnt = gcnt[g];
    float inv = cnt > 0.f ? 1.f / cnt : 0.f;
    float mean = gsum[idx] * inv;
    float msw = ms[w];
    float var = gsumsq[idx] * inv - mean * mean * msw * (2.f - msw);
    var = fmaxf(var, 0.f);
    float sc = wgt[w] * rsqrtf(var + GN_EPS);
    scalev[idx] = sc;
    shiftv[idx] = bias[w] - sc * msw * mean;
}

// ---------------- normalize: xn = scale*x + shift (bf16 out), float4 lanes ----
__global__ __launch_bounds__(256) void normalize_kernel(
    const float* __restrict__ x, const int* __restrict__ batch,
    const float* __restrict__ scalev, const float* __restrict__ shiftv,
    __hip_bfloat16* __restrict__ xn, int N)
{
    size_t tid = (size_t)blockIdx.x * blockDim.x + threadIdx.x;   // one per 4 elems
    if (tid >= (size_t)N * (WW / 4)) return;
    int row = (int)(tid >> 5);
    int c4 = (int)(tid & 31) * 4;
    int g = batch[row];
    float4 v = *(const float4*)(x + (size_t)row * WW + c4);
    float4 sc = *(const float4*)(scalev + (size_t)g * WW + c4);
    float4 sh = *(const float4*)(shiftv + (size_t)g * WW + c4);
    __hip_bfloat162 o0, o1;
    o0.x = __float2bfloat16(sc.x * v.x + sh.x);
    o0.y = __float2bfloat16(sc.y * v.y + sh.y);
    o1.x = __float2bfloat16(sc.z * v.z + sh.z);
    o1.y = __float2bfloat16(sc.w * v.w + sh.w);
    union { __hip_bfloat162 h[2]; uint2 u; } pk;
    pk.h[0] = o0; pk.h[1] = o1;
    *(uint2*)(xn + (size_t)row * WW + c4) = pk.u;
}

// ---------------- convert fp32 weight matrices -> bf16 ----------------
__global__ __launch_bounds__(256) void cvt_w_kernel(
    const float* __restrict__ w0, const float* __restrict__ w1,
    const float* __restrict__ w2, const float* __restrict__ w3,
    __hip_bfloat16* __restrict__ dst)
{
    int idx = blockIdx.x * blockDim.x + threadIdx.x;   // 0 .. 4*16384-1
    int m = idx >> 14;
    int o = idx & 16383;
    const float* src = (m == 0) ? w0 : (m == 1) ? w1 : (m == 2) ? w2 : w3;
    dst[idx] = __float2bfloat16(src[o]);
}

// ---------------- CSR build: histogram over dst ----------------
__global__ __launch_bounds__(256) void hist_kernel(
    const int* __restrict__ ei, int E, int* __restrict__ deg)
{
    int e = blockIdx.x * 256 + threadIdx.x;
    if (e < E) atomicAdd(&deg[ei[(size_t)E + e]], 1);
}

// ---------------- hierarchical exclusive scan (3 kernels) ----------------
__global__ __launch_bounds__(SCAN_B) void scan_blocks(
    const int* __restrict__ deg, int N, int* __restrict__ off, int* __restrict__ bsum)
{
    __shared__ int s[SCAN_B];
    int t = threadIdx.x;
    int i = blockIdx.x * SCAN_B + t;
    int v = (i < N) ? deg[i] : 0;
    s[t] = v; __syncthreads();
    for (int d = 1; d < SCAN_B; d <<= 1) {
        int tmp = (t >= d) ? s[t - d] : 0;
        __syncthreads();
        s[t] += tmp;
        __syncthreads();
    }
    if (i < N) off[i] = s[t] - v;                 // block-local exclusive
    if (t == SCAN_B - 1) bsum[blockIdx.x] = s[t]; // block total
}

__global__ __launch_bounds__(256) void scan_partials(int* __restrict__ bsum, int P)
{
    __shared__ int s[256];
    int t = threadIdx.x;
    int v = (t < P) ? bsum[t] : 0;
    s[t] = v; __syncthreads();
    for (int d = 1; d < 256; d <<= 1) {
        int tmp = (t >= d) ? s[t - d] : 0;
        __syncthreads();
        s[t] += tmp;
        __syncthreads();
    }
    if (t < P) bsum[t] = s[t] - v;                // exclusive, in place
}

__global__ __launch_bounds__(SCAN_B) void add_offsets(
    int* __restrict__ off, const int* __restrict__ bsum, int N)
{
    int i = blockIdx.x * SCAN_B + threadIdx.x;
    if (i < N) off[i] += bsum[blockIdx.x];
}

// ---------------- placement v2: 4 edges/thread, batched chains ---------------
__global__ __launch_bounds__(256) void place_kernel(
    const int* __restrict__ ei, const float* __restrict__ ew,
    const int* __restrict__ off, int* __restrict__ cursor,
    int2* __restrict__ ebuf, int E)
{
    int base = blockIdx.x * 1024 + threadIdx.x;
    int dstv[4], srcv[4];
    float wv[4];
    int slot[4];
#pragma unroll
    for (int i = 0; i < 4; ++i) {
        int e = base + i * 256;
        dstv[i] = (e < E) ? ei[(size_t)E + e] : -1;
    }
#pragma unroll
    for (int i = 0; i < 4; ++i) {
        int e = base + i * 256;
        if (e < E) { srcv[i] = ei[e]; wv[i] = ew[e]; }
    }
#pragma unroll
    for (int i = 0; i < 4; ++i)
        if (dstv[i] >= 0) slot[i] = off[dstv[i]] + atomicAdd(&cursor[dstv[i]], 1);
#pragma unroll
    for (int i = 0; i < 4; ++i)
        if (dstv[i] >= 0) ebuf[slot[i]] = make_int2(srcv[i], __float_as_int(wv[i]));
}

// ---------------- fused gather+GEMM v11: LDS-staged edges, 4-wide gather -----
// R6 localized the cost: FETCH already at the logical floor; the kernel is
// latency-bound on the gather chain (ebuf-L2 hop -> row load, serialized per
// 2 edges). v11: (a) stage the block's contiguous ebuf slice [off[rb],
// off[rb+32]) into LDS via global_load_lds pairs (<=256 instrs, prefetched
// under the same barrier as A2 staging) -- removes the ~200cy ebuf hop from
// every iteration; (b) 4-wide row unroll -> 8 independent 16B row loads in
// flight per iteration, chain ~= ceil(d/4)*(LDS+row) vs ceil(d/2)*(L2+row).
// Capacity 512 entries (22 sigma above Poisson(200) block mean); predicated
// global fallback keeps correctness regardless.
// Epilogue/W layout: adjacent-pair cols (wave*32 + 2*r16 + tt), packed
// bf16x2/float2 stores. LDS swizzle (involution): slot s of row r holds chunk
// s^(r&15); all writers/readers XOR the same.
// C/D layout: col=lane&15, row=(lane>>4)*4+reg (m89-verified).
template <bool OUT_BF16>
__global__ __launch_bounds__(256, 4) void fused_kernel(
    const __hip_bfloat16* __restrict__ X,
    const int2* __restrict__ ebuf, const int* __restrict__ off,
    const int* __restrict__ deg,
    const __hip_bfloat16* __restrict__ Wrel, const __hip_bfloat16* __restrict__ Wroot,
    const float* __restrict__ bias, const float* __restrict__ resid,
    void* __restrict__ outv, int N, int leaky)
{
    __shared__ __align__(16) __hip_bfloat16 smem[2 * 32 * 128];   // 16 KB
    __shared__ __align__(16) int2 eshare[512];                    // 4 KB
    int tid = threadIdx.x;
    int wave = tid >> 6, lane = tid & 63;
    int q = lane >> 4, r16 = lane & 15;
    int rb = blockIdx.x * 32;

    // ---- (1a) A2 staging: 8 x 1KB instructions, 2 per wave (async) ----
#pragma unroll
    for (int s = 0; s < 2; ++s) {
        int t = wave * 2 + s;                     // 0..7, rows t*4..t*4+3
        int rloc = t * 4 + (lane >> 4);
        int c = (lane & 15) ^ (rloc & 15);        // pre-swizzled global chunk
        int grow = rb + rloc; if (grow >= N) grow = N - 1;
        const __hip_bfloat16* g = X + (size_t)grow * WW + c * 8;
        __hip_bfloat16* l = smem + 4096 + t * 512;   // linear LDS dest
        __builtin_amdgcn_global_load_lds(
            (const __attribute__((address_space(1))) void*)g,
            (__attribute__((address_space(3))) void*)l, 16, 0, 0);
    }

    // ---- (1b) ebuf slice staging: entries [e0, e0+nstage) -> eshare ----
    int endn = min(rb + 32, N) - 1;
    int e0 = off[rb];
    int ne = off[endn] + deg[endn] - e0;
    int nstage = min(ne, 512);
    {
        int pairs = (nstage + 1) >> 1;            // <= 256: one instr/thread
        if (tid < pairs) {
            // global per-lane addr; LDS dest = wave-uniform base + lane*16
            const int2* g = ebuf + e0 + 2 * tid;  // odd-tail 8B overread stays
                                                  // inside the workspace
            int2* l = eshare + 2 * (wave * 64);
            __builtin_amdgcn_global_load_lds(
                (const __attribute__((address_space(1))) void*)g,
                (__attribute__((address_space(3))) void*)l, 16, 0, 0);
        }
    }
    __syncthreads();   // vmcnt(0): A2 + edge slice resident

    // ---- (2) gather: node = rb + tid>>3, cols (tid&7)*16..+15 ----
    int node = rb + (tid >> 3);
    int nc = node < N ? node : N - 1;
    int start = off[nc];
    int d = (node < N) ? deg[nc] : 0;
    int lb = start - e0;                          // local index into eshare
    int sub = tid & 7;
    float a16[16];
#pragma unroll
    for (int j = 0; j < 16; ++j) a16[j] = 0.f;
    int last = d - 1;                             // d==0 -> loop skipped
    for (int k = 0; k <= last; k += 4) {
        int j1 = min(k + 1, last);
        int j2 = min(k + 2, last);
        int j3 = min(k + 3, last);
        int2 p0, p1, p2, p3;
        if (lb + j3 < nstage) {                   // common case: all staged
            p0 = eshare[lb + k];
            p1 = eshare[lb + j1];
            p2 = eshare[lb + j2];
            p3 = eshare[lb + j3];
        } else {                                  // ~never (block ne > 512)
            p0 = (lb + k  < nstage) ? eshare[lb + k]  : ebuf[start + k];
            p1 = (lb + j1 < nstage) ? eshare[lb + j1] : ebuf[start + j1];
            p2 = (lb + j2 < nstage) ? eshare[lb + j2] : ebuf[start + j2];
            p3 = (lb + j3 < nstage) ? eshare[lb + j3] : ebuf[start + j3];
        }
        const __hip_bfloat16* r0 = X + (size_t)p0.x * WW + sub * 16;
        const __hip_bfloat16* r1 = X + (size_t)p1.x * WW + sub * 16;
        const __hip_bfloat16* r2 = X + (size_t)p2.x * WW + sub * 16;
        const __hip_bfloat16* r3 = X + (size_t)p3.x * WW + sub * 16;
        short8 a0 = *(const short8*)(r0);
        short8 b0 = *(const short8*)(r0 + 8);
        short8 a1 = *(const short8*)(r1);
        short8 b1 = *(const short8*)(r1 + 8);
        short8 a2 = *(const short8*)(r2);
        short8 b2 = *(const short8*)(r2 + 8);
        short8 a3 = *(const short8*)(r3);
        short8 b3 = *(const short8*)(r3 + 8);
        float w0 = __int_as_float(p0.y);
        float w1 = (k + 1 <= last) ? __int_as_float(p1.y) : 0.f;
        float w2 = (k + 2 <= last) ? __int_as_float(p2.y) : 0.f;
        float w3 = (k + 3 <= last) ? __int_as_float(p3.y) : 0.f;
#pragma unroll
        for (int j = 0; j < 8; ++j) {
            a16[j]     += w0 * bfbits2f(a0[j]) + w1 * bfbits2f(a1[j]);
            a16[8 + j] += w0 * bfbits2f(b0[j]) + w1 * bfbits2f(b1[j]);
            a16[j]     += w2 * bfbits2f(a2[j]) + w3 * bfbits2f(a3[j]);
            a16[8 + j] += w2 * bfbits2f(b2[j]) + w3 * bfbits2f(b3[j]);
        }
    }

    // ---- (3) agg -> A1 LDS region, swizzled (chunks 2*sub, 2*sub+1) ----
    {
        int r = tid >> 3;                          // local row 0..31
        short8 pk0, pk1;
#pragma unroll
        for (int j = 0; j < 8; ++j) {
            pk0[j] = f2bfbits(a16[j]);
            pk1[j] = f2bfbits(a16[8 + j]);
        }
        int s0 = (2 * sub)     ^ (r & 15);
        int s1 = (2 * sub + 1) ^ (r & 15);
        *(short8*)(smem + r * 128 + s0 * 8) = pk0;
        *(short8*)(smem + r * 128 + s1 * 8) = pk1;
    }

    // ---- W fragments: adjacent-pair cols (wave*32 + 2*r16 + tt) ----
    short8 wf[8][2];
#pragma unroll
    for (int kc = 0; kc < 8; ++kc) {
        const __hip_bfloat16* Wsel = (kc < 4) ? Wrel : Wroot;
        int koff = (kc & 3) * 32 + q * 8;
#pragma unroll
        for (int tt = 0; tt < 2; ++tt) {
            int col = wave * 32 + 2 * r16 + tt;
            wf[kc][tt] = *(const short8*)(Wsel + ((size_t)col * WW + koff));
        }
    }
    float bcol[2];
#pragma unroll
    for (int tt = 0; tt < 2; ++tt) bcol[tt] = bias[wave * 32 + 2 * r16 + tt];

    __syncthreads();   // drains lgkm (A1 written); A2 already resident

    // ---- (5) MFMA: kc<4 A1*Wrel, kc>=4 A2*Wroot ----
    floatx4 acc[2][2];
#pragma unroll
    for (int r = 0; r < 2; ++r)
#pragma unroll
        for (int tt = 0; tt < 2; ++tt) acc[r][tt] = (floatx4){0.f, 0.f, 0.f, 0.f};

#pragma unroll
    for (int kc = 0; kc < 8; ++kc) {
        int m = kc >> 2;
        short8 af[2];
#pragma unroll
        for (int r = 0; r < 2; ++r) {
            int row = r * 16 + r16;
            int slot = ((kc & 3) * 4 + q) ^ r16;       // row&15 == r16
            af[r] = *(const short8*)(&smem[m * 4096 + row * 128 + slot * 8]);
        }
#pragma unroll
        for (int r = 0; r < 2; ++r) {
            acc[r][0] = __builtin_amdgcn_mfma_f32_16x16x32_bf16(af[r], wf[kc][0], acc[r][0], 0, 0, 0);
            acc[r][1] = __builtin_amdgcn_mfma_f32_16x16x32_bf16(af[r], wf[kc][1], acc[r][1], 0, 0, 0);
        }
    }

    // ---- epilogue: packed adjacent-col stores ----
    int colb = wave * 32 + 2 * r16;
#pragma unroll
    for (int r = 0; r < 2; ++r)
#pragma unroll
        for (int rr = 0; rr < 4; ++rr) {
            int row = rb + r * 16 + q * 4 + rr;
            if (row < N) {
                float v0 = acc[r][0][rr] + bcol[0];
                float v1 = acc[r][1][rr] + bcol[1];
                if (leaky) {
                    v0 = v0 >= 0.f ? v0 : 0.1f * v0;
                    v1 = v1 >= 0.f ? v1 : 0.1f * v1;
                }
                if (OUT_BF16) {
                    __hip_bfloat162 o;
                    o.x = __float2bfloat16(v0);
                    o.y = __float2bfloat16(v1);
                    *(__hip_bfloat162*)((__hip_bfloat16*)outv + (size_t)row * WW + colb) = o;
                } else {
                    float2 rv = *(const float2*)(resid + (size_t)row * WW + colb);
                    float2 o;
                    o.x = v0 + rv.x;
                    o.y = v1 + rv.y;
                    *(float2*)((float*)outv + (size_t)row * WW + colb) = o;
                }
            }
        }
}

extern "C" void kernel_launch(void* const* d_in, const int* in_sizes, int n_in,
                              void* d_out, int out_size, void* d_ws, size_t ws_size,
                              hipStream_t stream) {
    const float* x      = (const float*)d_in[0];
    const int*   ei     = (const int*)d_in[1];
    const float* ew     = (const float*)d_in[2];
    const int*   batch  = (const int*)d_in[3];
    const float* gnw    = (const float*)d_in[4];
    const float* gnb    = (const float*)d_in[5];
    const float* gnm    = (const float*)d_in[6];
    const float* Wrel1  = (const float*)d_in[7];
    const float* brel1  = (const float*)d_in[8];
    const float* Wroot1 = (const float*)d_in[9];
    const float* Wrel2  = (const float*)d_in[10];
    const float* brel2  = (const float*)d_in[11];
    const float* Wroot2 = (const float*)d_in[12];

    int N = in_sizes[0] / WW;
    int E = in_sizes[1] / 2;
    int P = (N + SCAN_B - 1) / SCAN_B;   // scan partial count (98 for N=100k)
    int ntiles = (N + 31) / 32;          // 32-row tiles (3125)

    // workspace layout (8-byte aligned):
    // xn | y1 (bf16 N*W each) | Wb (bf16 4*W*W) | ebuf (int2 E)
    // | deg | cursor | gsum | gsumsq | gcnt | scalev | shiftv | off | bsum
    __hip_bfloat16* xn = (__hip_bfloat16*)d_ws;
    __hip_bfloat16* y1 = xn + (size_t)N * WW;
    __hip_bfloat16* Wb = y1 + (size_t)N * WW;       // [Wrel1|Wroot1|Wrel2|Wroot2]
    int2* ebuf   = (int2*)(Wb + 4 * WW * WW);
    int*  deg    = (int*)(ebuf + E);
    int*  cursor = deg + N;
    float* gsum   = (float*)(cursor + N);
    float* gsumsq = gsum + GG * WW;
    float* gcnt   = gsumsq + GG * WW;               // GG floats
    float* scalev = gcnt + GG;
    float* shiftv = scalev + GG * WW;
    int*  off    = (int*)(shiftv + GG * WW);
    int*  bsum   = off + N;

    // one memset covers deg, cursor, gsum, gsumsq, gcnt (contiguous)
    hipMemsetAsync(deg, 0, ((size_t)2 * N + 2 * GG * WW + GG) * sizeof(int), stream);

    // ---- CSR build (once; reused by both layers) ----
    hist_kernel<<<(E + 255) / 256, 256, 0, stream>>>(ei, E, deg);
    scan_blocks<<<P, SCAN_B, 0, stream>>>(deg, N, off, bsum);
    scan_partials<<<1, 256, 0, stream>>>(bsum, P);
    add_offsets<<<P, SCAN_B, 0, stream>>>(off, bsum, N);
    place_kernel<<<(E + 1023) / 1024, 256, 0, stream>>>(ei, ew, off, cursor, ebuf, E);

    // ---- GraphNorm ----
    cvt_w_kernel<<<(4 * WW * WW) / 256, 256, 0, stream>>>(Wrel1, Wroot1, Wrel2, Wroot2, Wb);
    stats_kernel<<<(N + 31) / 32, 128, 0, stream>>>(x, batch, N, gsum, gsumsq, gcnt);
    finalize_kernel<<<(GG * WW + 255) / 256, 256, 0, stream>>>(
        gsum, gsumsq, gcnt, gnw, gnb, gnm, scalev, shiftv);
    normalize_kernel<<<(int)(((size_t)N * (WW / 4) + 255) / 256), 256, 0, stream>>>(
        x, batch, scalev, shiftv, xn, N);

    // ---- layer 1: fused gather+GEMM (+bias+leaky) ----
    fused_kernel<true><<<ntiles, 256, 0, stream>>>(
        xn, ebuf, off, deg, Wb, Wb + WW * WW, brel1, nullptr, y1, N, 1);

    // ---- layer 2: fused gather+GEMM (+bias+residual) ----
    fused_kernel<false><<<ntiles, 256, 0, stream>>>(
        y1, ebuf, off, deg, Wb + 2 * WW * WW, Wb + 3 * WW * WW, brel2, x, d_out, N, 0);
}

// Round 8
// 313.678 us; speedup vs baseline: 1.3965x; 1.0328x over previous
//
#include <hip/hip_runtime.h>
#include <hip/hip_bf16.h>

#define WW 128
#define GG 64
#define GN_EPS 1e-5f
#define SCAN_B 1024

typedef __attribute__((ext_vector_type(8))) short short8;
typedef __attribute__((ext_vector_type(4))) float floatx4;

__device__ inline float bf2f(__hip_bfloat16 h) { return __bfloat162float(h); }
__device__ inline float bfbits2f(short v) {
    return __uint_as_float(((unsigned)(unsigned short)v) << 16);
}
__device__ inline short f2bfbits(float f) {
    __hip_bfloat16 h = __float2bfloat16(f);
    return *reinterpret_cast<short*>(&h);
}

// ---------------- prep1: hist (4 edges/thread) U stats (64 rows) U cvt_w ----
// All three are mutually independent; merging removes 2 launches and hides
// hist's atomic latency under stats' streaming loads (co-resident blocks).
__global__ __launch_bounds__(256) void prep1_kernel(
    // hist part
    const int* __restrict__ ei, int E, int* __restrict__ deg, int HB,
    // stats part
    const float* __restrict__ x, const int* __restrict__ batch, int N, int SB,
    float* __restrict__ gsum, float* __restrict__ gsumsq, float* __restrict__ gcnt,
    // cvt part
    const float* __restrict__ w0, const float* __restrict__ w1,
    const float* __restrict__ w2, const float* __restrict__ w3,
    __hip_bfloat16* __restrict__ wdst)
{
    int bid = blockIdx.x;
    int tid = threadIdx.x;

    if (bid < HB) {
        // ---- hist: 4 edges/thread, batched loads then batched atomics ----
        int base = bid * 1024 + tid;
        int d0 = (base             < E) ? ei[(size_t)E + base]       : -1;
        int d1 = (base + 256       < E) ? ei[(size_t)E + base + 256] : -1;
        int d2 = (base + 512       < E) ? ei[(size_t)E + base + 512] : -1;
        int d3 = (base + 768       < E) ? ei[(size_t)E + base + 768] : -1;
        if (d0 >= 0) atomicAdd(&deg[d0], 1);
        if (d1 >= 0) atomicAdd(&deg[d1], 1);
        if (d2 >= 0) atomicAdd(&deg[d2], 1);
        if (d3 >= 0) atomicAdd(&deg[d3], 1);
        return;
    }
    if (bid < HB + SB) {
        // ---- stats: 64 rows/block as two independent 32-row halves ----
        int sb = bid - HB;
        int half = tid >> 7;             // 0 or 1
        int w = tid & 127;
        int row0 = sb * 64 + half * 32;
        if (row0 >= N) return;
        int row1 = min(row0 + 32, N);
        float s = 0.f, ss = 0.f;
        int cur = batch[row0];
        int cnt = 0;
        auto flush = [&]() {
            atomicAdd(&gsum[cur * WW + w], s);
            atomicAdd(&gsumsq[cur * WW + w], ss);
            if (w == 0) atomicAdd(&gcnt[cur], (float)cnt);
            s = 0.f; ss = 0.f; cnt = 0;
        };
        int i = row0;
        for (; i + 4 <= row1; i += 4) {
            int g0 = batch[i + 0], g1 = batch[i + 1], g2 = batch[i + 2], g3 = batch[i + 3];
            float v0 = x[(size_t)(i + 0) * WW + w];
            float v1 = x[(size_t)(i + 1) * WW + w];
            float v2 = x[(size_t)(i + 2) * WW + w];
            float v3 = x[(size_t)(i + 3) * WW + w];
            if (g0 != cur) { flush(); cur = g0; }
            s += v0; ss += v0 * v0; ++cnt;
            if (g1 != cur) { flush(); cur = g1; }
            s += v1; ss += v1 * v1; ++cnt;
            if (g2 != cur) { flush(); cur = g2; }
            s += v2; ss += v2 * v2; ++cnt;
            if (g3 != cur) { flush(); cur = g3; }
            s += v3; ss += v3 * v3; ++cnt;
        }
        for (; i < row1; ++i) {
            int g = batch[i];
            float v = x[(size_t)i * WW + w];
            if (g != cur) { flush(); cur = g; }
            s += v; ss += v * v; ++cnt;
        }
        flush();
        return;
    }
    // ---- cvt_w: fp32 -> bf16, 4*128*128 elements over 256 blocks ----
    int idx = (bid - HB - SB) * 256 + tid;        // 0 .. 65535
    int m = idx >> 14;
    int o = idx & 16383;
    const float* src = (m == 0) ? w0 : (m == 1) ? w1 : (m == 2) ? w2 : w3;
    wdst[idx] = __float2bfloat16(src[o]);
}

// ---------------- hierarchical exclusive scan (2 kernels) ----------------
__global__ __launch_bounds__(SCAN_B) void scan_blocks(
    const int* __restrict__ deg, int N, int* __restrict__ off, int* __restrict__ bsum)
{
    __shared__ int s[SCAN_B];
    int t = threadIdx.x;
    int i = blockIdx.x * SCAN_B + t;
    int v = (i < N) ? deg[i] : 0;
    s[t] = v; __syncthreads();
    for (int d = 1; d < SCAN_B; d <<= 1) {
        int tmp = (t >= d) ? s[t - d] : 0;
        __syncthreads();
        s[t] += tmp;
        __syncthreads();
    }
    if (i < N) off[i] = s[t] - v;                 // block-local exclusive
    if (t == SCAN_B - 1) bsum[blockIdx.x] = s[t]; // block total (raw)
}

// add_offsets v2: absorbs scan_partials — each block reduces bsum[0..bid)
// itself (P<=98 raw totals; threads t<bid contribute, tree-reduce in LDS).
__global__ __launch_bounds__(SCAN_B) void add_offsets2(
    int* __restrict__ off, const int* __restrict__ bsum, int N)
{
    __shared__ int red[SCAN_B];
    int t = threadIdx.x;
    red[t] = (t < blockIdx.x) ? bsum[t] : 0;      // P <= SCAN_B guaranteed
    __syncthreads();
    for (int s = SCAN_B / 2; s > 0; s >>= 1) {
        if (t < s) red[t] += red[t + s];
        __syncthreads();
    }
    int i = blockIdx.x * SCAN_B + t;
    if (i < N) off[i] += red[0];
}

// ---------------- place_fin: place (4 edges/thread, nt stores) U finalize ----
__global__ __launch_bounds__(256) void place_fin_kernel(
    // place part
    const int* __restrict__ ei, const float* __restrict__ ew,
    const int* __restrict__ off, int* __restrict__ cursor,
    int2* __restrict__ ebuf, int E, int PB,
    // finalize part
    const float* __restrict__ gsum, const float* __restrict__ gsumsq,
    const float* __restrict__ gcnt,
    const float* __restrict__ wgt, const float* __restrict__ bias,
    const float* __restrict__ ms,
    float* __restrict__ scalev, float* __restrict__ shiftv)
{
    int bid = blockIdx.x;
    int tid = threadIdx.x;

    if (bid < PB) {
        int base = bid * 1024 + tid;
        int dstv[4], srcv[4];
        float wv[4];
        int slot[4];
#pragma unroll
        for (int i = 0; i < 4; ++i) {
            int e = base + i * 256;
            dstv[i] = (e < E) ? ei[(size_t)E + e] : -1;
        }
#pragma unroll
        for (int i = 0; i < 4; ++i) {
            int e = base + i * 256;
            if (e < E) { srcv[i] = ei[e]; wv[i] = ew[e]; }
        }
#pragma unroll
        for (int i = 0; i < 4; ++i)
            if (dstv[i] >= 0) slot[i] = off[dstv[i]] + atomicAdd(&cursor[dstv[i]], 1);
#pragma unroll
        for (int i = 0; i < 4; ++i)
            if (dstv[i] >= 0) {
                unsigned long long v = (unsigned)srcv[i]
                    | ((unsigned long long)__float_as_uint(wv[i]) << 32);
                __builtin_nontemporal_store(v, (unsigned long long*)&ebuf[slot[i]]);
            }
        return;
    }
    // ---- finalize: 32 blocks x 256 = 8192 (g,w) cells ----
    int idx = (bid - PB) * 256 + tid;
    if (idx >= GG * WW) return;
    int g = idx >> 7, w = idx & (WW - 1);
    float cnt = gcnt[g];
    float inv = cnt > 0.f ? 1.f / cnt : 0.f;
    float mean = gsum[idx] * inv;
    float msw = ms[w];
    float var = gsumsq[idx] * inv - mean * mean * msw * (2.f - msw);
    var = fmaxf(var, 0.f);
    float sc = wgt[w] * rsqrtf(var + GN_EPS);
    scalev[idx] = sc;
    shiftv[idx] = bias[w] - sc * msw * mean;
}

// ---------------- normalize v2: 8 elems/thread, 16B stores ----------------
__global__ __launch_bounds__(256) void normalize_kernel(
    const float* __restrict__ x, const int* __restrict__ batch,
    const float* __restrict__ scalev, const float* __restrict__ shiftv,
    __hip_bfloat16* __restrict__ xn, int N)
{
    size_t tid = (size_t)blockIdx.x * blockDim.x + threadIdx.x;   // one per 8 elems
    if (tid >= (size_t)N * (WW / 8)) return;
    int row = (int)(tid >> 4);
    int c8 = (int)(tid & 15) * 8;
    int g = batch[row];
    const float* xb = x + (size_t)row * WW + c8;
    const float* scb = scalev + (size_t)g * WW + c8;
    const float* shb = shiftv + (size_t)g * WW + c8;
    float4 v0 = *(const float4*)(xb);
    float4 v1 = *(const float4*)(xb + 4);
    float4 sc0 = *(const float4*)(scb);
    float4 sc1 = *(const float4*)(scb + 4);
    float4 sh0 = *(const float4*)(shb);
    float4 sh1 = *(const float4*)(shb + 4);
    union { short s[8]; uint4 u; } pk;
    pk.s[0] = f2bfbits(sc0.x * v0.x + sh0.x);
    pk.s[1] = f2bfbits(sc0.y * v0.y + sh0.y);
    pk.s[2] = f2bfbits(sc0.z * v0.z + sh0.z);
    pk.s[3] = f2bfbits(sc0.w * v0.w + sh0.w);
    pk.s[4] = f2bfbits(sc1.x * v1.x + sh1.x);
    pk.s[5] = f2bfbits(sc1.y * v1.y + sh1.y);
    pk.s[6] = f2bfbits(sc1.z * v1.z + sh1.z);
    pk.s[7] = f2bfbits(sc1.w * v1.w + sh1.w);
    *(uint4*)(xn + (size_t)row * WW + c8) = pk.u;
}

// ---------------- fused gather+GEMM v11 (unchanged from R7, verified) --------
// LDS-staged edge slice + 4-wide gather + A2 via global_load_lds + MFMA.
// LDS swizzle (involution): slot s of row r holds chunk s^(r&15).
// C/D layout: col=lane&15, row=(lane>>4)*4+reg (m89-verified).
template <bool OUT_BF16>
__global__ __launch_bounds__(256, 4) void fused_kernel(
    const __hip_bfloat16* __restrict__ X,
    const int2* __restrict__ ebuf, const int* __restrict__ off,
    const int* __restrict__ deg,
    const __hip_bfloat16* __restrict__ Wrel, const __hip_bfloat16* __restrict__ Wroot,
    const float* __restrict__ bias, const float* __restrict__ resid,
    void* __restrict__ outv, int N, int leaky)
{
    __shared__ __align__(16) __hip_bfloat16 smem[2 * 32 * 128];   // 16 KB
    __shared__ __align__(16) int2 eshare[512];                    // 4 KB
    int tid = threadIdx.x;
    int wave = tid >> 6, lane = tid & 63;
    int q = lane >> 4, r16 = lane & 15;
    int rb = blockIdx.x * 32;

    // ---- (1a) A2 staging: 8 x 1KB instructions, 2 per wave (async) ----
#pragma unroll
    for (int s = 0; s < 2; ++s) {
        int t = wave * 2 + s;                     // 0..7, rows t*4..t*4+3
        int rloc = t * 4 + (lane >> 4);
        int c = (lane & 15) ^ (rloc & 15);        // pre-swizzled global chunk
        int grow = rb + rloc; if (grow >= N) grow = N - 1;
        const __hip_bfloat16* g = X + (size_t)grow * WW + c * 8;
        __hip_bfloat16* l = smem + 4096 + t * 512;   // linear LDS dest
        __builtin_amdgcn_global_load_lds(
            (const __attribute__((address_space(1))) void*)g,
            (__attribute__((address_space(3))) void*)l, 16, 0, 0);
    }

    // ---- (1b) ebuf slice staging: entries [e0, e0+nstage) -> eshare ----
    int endn = min(rb + 32, N) - 1;
    int e0 = off[rb];
    int ne = off[endn] + deg[endn] - e0;
    int nstage = min(ne, 512);
    {
        int pairs = (nstage + 1) >> 1;            // <= 256: one instr/thread
        if (tid < pairs) {
            const int2* g = ebuf + e0 + 2 * tid;
            int2* l = eshare + 2 * (wave * 64);
            __builtin_amdgcn_global_load_lds(
                (const __attribute__((address_space(1))) void*)g,
                (__attribute__((address_space(3))) void*)l, 16, 0, 0);
        }
    }
    __syncthreads();   // vmcnt(0): A2 + edge slice resident

    // ---- (2) gather: node = rb + tid>>3, cols (tid&7)*16..+15 ----
    int node = rb + (tid >> 3);
    int nc = node < N ? node : N - 1;
    int start = off[nc];
    int d = (node < N) ? deg[nc] : 0;
    int lb = start - e0;                          // local index into eshare
    int sub = tid & 7;
    float a16[16];
#pragma unroll
    for (int j = 0; j < 16; ++j) a16[j] = 0.f;
    int last = d - 1;                             // d==0 -> loop skipped
    for (int k = 0; k <= last; k += 4) {
        int j1 = min(k + 1, last);
        int j2 = min(k + 2, last);
        int j3 = min(k + 3, last);
        int2 p0, p1, p2, p3;
        if (lb + j3 < nstage) {                   // common case: all staged
            p0 = eshare[lb + k];
            p1 = eshare[lb + j1];
            p2 = eshare[lb + j2];
            p3 = eshare[lb + j3];
        } else {                                  // ~never (block ne > 512)
            p0 = (lb + k  < nstage) ? eshare[lb + k]  : ebuf[start + k];
            p1 = (lb + j1 < nstage) ? eshare[lb + j1] : ebuf[start + j1];
            p2 = (lb + j2 < nstage) ? eshare[lb + j2] : ebuf[start + j2];
            p3 = (lb + j3 < nstage) ? eshare[lb + j3] : ebuf[start + j3];
        }
        const __hip_bfloat16* r0 = X + (size_t)p0.x * WW + sub * 16;
        const __hip_bfloat16* r1 = X + (size_t)p1.x * WW + sub * 16;
        const __hip_bfloat16* r2 = X + (size_t)p2.x * WW + sub * 16;
        const __hip_bfloat16* r3 = X + (size_t)p3.x * WW + sub * 16;
        short8 a0 = *(const short8*)(r0);
        short8 b0 = *(const short8*)(r0 + 8);
        short8 a1 = *(const short8*)(r1);
        short8 b1 = *(const short8*)(r1 + 8);
        short8 a2 = *(const short8*)(r2);
        short8 b2 = *(const short8*)(r2 + 8);
        short8 a3 = *(const short8*)(r3);
        short8 b3 = *(const short8*)(r3 + 8);
        float w0 = __int_as_float(p0.y);
        float w1 = (k + 1 <= last) ? __int_as_float(p1.y) : 0.f;
        float w2 = (k + 2 <= last) ? __int_as_float(p2.y) : 0.f;
        float w3 = (k + 3 <= last) ? __int_as_float(p3.y) : 0.f;
#pragma unroll
        for (int j = 0; j < 8; ++j) {
            a16[j]     += w0 * bfbits2f(a0[j]) + w1 * bfbits2f(a1[j]);
            a16[8 + j] += w0 * bfbits2f(b0[j]) + w1 * bfbits2f(b1[j]);
            a16[j]     += w2 * bfbits2f(a2[j]) + w3 * bfbits2f(a3[j]);
            a16[8 + j] += w2 * bfbits2f(b2[j]) + w3 * bfbits2f(b3[j]);
        }
    }

    // ---- (3) agg -> A1 LDS region, swizzled (chunks 2*sub, 2*sub+1) ----
    {
        int r = tid >> 3;                          // local row 0..31
        short8 pk0, pk1;
#pragma unroll
        for (int j = 0; j < 8; ++j) {
            pk0[j] = f2bfbits(a16[j]);
            pk1[j] = f2bfbits(a16[8 + j]);
        }
        int s0 = (2 * sub)     ^ (r & 15);
        int s1 = (2 * sub + 1) ^ (r & 15);
        *(short8*)(smem + r * 128 + s0 * 8) = pk0;
        *(short8*)(smem + r * 128 + s1 * 8) = pk1;
    }

    // ---- W fragments: adjacent-pair cols (wave*32 + 2*r16 + tt) ----
    short8 wf[8][2];
#pragma unroll
    for (int kc = 0; kc < 8; ++kc) {
        const __hip_bfloat16* Wsel = (kc < 4) ? Wrel : Wroot;
        int koff = (kc & 3) * 32 + q * 8;
#pragma unroll
        for (int tt = 0; tt < 2; ++tt) {
            int col = wave * 32 + 2 * r16 + tt;
            wf[kc][tt] = *(const short8*)(Wsel + ((size_t)col * WW + koff));
        }
    }
    float bcol[2];
#pragma unroll
    for (int tt = 0; tt < 2; ++tt) bcol[tt] = bias[wave * 32 + 2 * r16 + tt];

    __syncthreads();   // drains lgkm (A1 written); A2 already resident

    // ---- (5) MFMA: kc<4 A1*Wrel, kc>=4 A2*Wroot ----
    floatx4 acc[2][2];
#pragma unroll
    for (int r = 0; r < 2; ++r)
#pragma unroll
        for (int tt = 0; tt < 2; ++tt) acc[r][tt] = (floatx4){0.f, 0.f, 0.f, 0.f};

#pragma unroll
    for (int kc = 0; kc < 8; ++kc) {
        int m = kc >> 2;
        short8 af[2];
#pragma unroll
        for (int r = 0; r < 2; ++r) {
            int row = r * 16 + r16;
            int slot = ((kc & 3) * 4 + q) ^ r16;       // row&15 == r16
            af[r] = *(const short8*)(&smem[m * 4096 + row * 128 + slot * 8]);
        }
#pragma unroll
        for (int r = 0; r < 2; ++r) {
            acc[r][0] = __builtin_amdgcn_mfma_f32_16x16x32_bf16(af[r], wf[kc][0], acc[r][0], 0, 0, 0);
            acc[r][1] = __builtin_amdgcn_mfma_f32_16x16x32_bf16(af[r], wf[kc][1], acc[r][1], 0, 0, 0);
        }
    }

    // ---- epilogue: packed adjacent-col stores ----
    int colb = wave * 32 + 2 * r16;
#pragma unroll
    for (int r = 0; r < 2; ++r)
#pragma unroll
        for (int rr = 0; rr < 4; ++rr) {
            int row = rb + r * 16 + q * 4 + rr;
            if (row < N) {
                float v0 = acc[r][0][rr] + bcol[0];
                float v1 = acc[r][1][rr] + bcol[1];
                if (leaky) {
                    v0 = v0 >= 0.f ? v0 : 0.1f * v0;
                    v1 = v1 >= 0.f ? v1 : 0.1f * v1;
                }
                if (OUT_BF16) {
                    __hip_bfloat162 o;
                    o.x = __float2bfloat16(v0);
                    o.y = __float2bfloat16(v1);
                    *(__hip_bfloat162*)((__hip_bfloat16*)outv + (size_t)row * WW + colb) = o;
                } else {
                    float2 rv = *(const float2*)(resid + (size_t)row * WW + colb);
                    float2 o;
                    o.x = v0 + rv.x;
                    o.y = v1 + rv.y;
                    *(float2*)((float*)outv + (size_t)row * WW + colb) = o;
                }
            }
        }
}

extern "C" void kernel_launch(void* const* d_in, const int* in_sizes, int n_in,
                              void* d_out, int out_size, void* d_ws, size_t ws_size,
                              hipStream_t stream) {
    const float* x      = (const float*)d_in[0];
    const int*   ei     = (const int*)d_in[1];
    const float* ew     = (const float*)d_in[2];
    const int*   batch  = (const int*)d_in[3];
    const float* gnw    = (const float*)d_in[4];
    const float* gnb    = (const float*)d_in[5];
    const float* gnm    = (const float*)d_in[6];
    const float* Wrel1  = (const float*)d_in[7];
    const float* brel1  = (const float*)d_in[8];
    const float* Wroot1 = (const float*)d_in[9];
    const float* Wrel2  = (const float*)d_in[10];
    const float* brel2  = (const float*)d_in[11];
    const float* Wroot2 = (const float*)d_in[12];

    int N = in_sizes[0] / WW;
    int E = in_sizes[1] / 2;
    int P = (N + SCAN_B - 1) / SCAN_B;   // scan partial count (98 for N=100k)
    int ntiles = (N + 31) / 32;          // 32-row tiles (3125)
    int HB = (E + 1023) / 1024;          // hist blocks (4 edges/thread)
    int SB = (N + 63) / 64;              // stats blocks (64 rows, 2 halves)
    int PB = (E + 1023) / 1024;          // place blocks
    int FB = (GG * WW + 255) / 256;      // finalize blocks (32)

    // workspace layout (8-byte aligned):
    // xn | y1 (bf16 N*W each) | Wb (bf16 4*W*W) | ebuf (int2 E)
    // | deg | cursor | gsum | gsumsq | gcnt | scalev | shiftv | off | bsum
    __hip_bfloat16* xn = (__hip_bfloat16*)d_ws;
    __hip_bfloat16* y1 = xn + (size_t)N * WW;
    __hip_bfloat16* Wb = y1 + (size_t)N * WW;       // [Wrel1|Wroot1|Wrel2|Wroot2]
    int2* ebuf   = (int2*)(Wb + 4 * WW * WW);
    int*  deg    = (int*)(ebuf + E);
    int*  cursor = deg + N;
    float* gsum   = (float*)(cursor + N);
    float* gsumsq = gsum + GG * WW;
    float* gcnt   = gsumsq + GG * WW;               // GG floats
    float* scalev = gcnt + GG;
    float* shiftv = scalev + GG * WW;
    int*  off    = (int*)(shiftv + GG * WW);
    int*  bsum   = off + N;

    // one memset covers deg, cursor, gsum, gsumsq, gcnt (contiguous)
    hipMemsetAsync(deg, 0, ((size_t)2 * N + 2 * GG * WW + GG) * sizeof(int), stream);

    // ---- prep1: hist U stats U cvt_w (independent, co-resident) ----
    prep1_kernel<<<HB + SB + 256, 256, 0, stream>>>(
        ei, E, deg, HB,
        x, batch, N, SB, gsum, gsumsq, gcnt,
        Wrel1, Wroot1, Wrel2, Wroot2, Wb);

    // ---- scan (2 kernels: block scan, then fused partials+apply) ----
    scan_blocks<<<P, SCAN_B, 0, stream>>>(deg, N, off, bsum);
    add_offsets2<<<P, SCAN_B, 0, stream>>>(off, bsum, N);

    // ---- place U finalize ----
    place_fin_kernel<<<PB + FB, 256, 0, stream>>>(
        ei, ew, off, cursor, ebuf, E, PB,
        gsum, gsumsq, gcnt, gnw, gnb, gnm, scalev, shiftv);

    // ---- normalize ----
    normalize_kernel<<<(int)(((size_t)N * (WW / 8) + 255) / 256), 256, 0, stream>>>(
        x, batch, scalev, shiftv, xn, N);

    // ---- layer 1: fused gather+GEMM (+bias+leaky) ----
    fused_kernel<true><<<ntiles, 256, 0, stream>>>(
        xn, ebuf, off, deg, Wb, Wb + WW * WW, brel1, nullptr, y1, N, 1);

    // ---- layer 2: fused gather+GEMM (+bias+residual) ----
    fused_kernel<false><<<ntiles, 256, 0, stream>>>(
        y1, ebuf, off, deg, Wb + 2 * WW * WW, Wb + 3 * WW * WW, brel2, x, d_out, N, 0);
}